// Round 14
// baseline (147.068 us; speedup 1.0000x reference)
//
#include <hip/hip_runtime.h>
#include <hip/hip_bf16.h>
#include <stdint.h>

// Problem constants: B=8, S=1024, D=1024, H=16, DH=64
typedef __bf16 bf16_t;
typedef bf16_t bf16x8 __attribute__((ext_vector_type(8)));
typedef float f32x4 __attribute__((ext_vector_type(4)));
typedef unsigned short ushortx8 __attribute__((ext_vector_type(8)));

__device__ __forceinline__ uint16_t f2bf(float f) {
  uint32_t u = __float_as_uint(f);
  uint32_t r = u + 0x7FFFu + ((u >> 16) & 1u);  // RNE
  return (uint16_t)(r >> 16);
}

__device__ __forceinline__ int read_len(const int* __restrict__ p, int b) {
  bool is64 = (p[1] == 0) | (p[3] == 0) | (p[5] == 0) | (p[7] == 0);
  return is64 ? p[2 * b] : p[b];
}

#define GLDS16(gp, lp)                                                   \
  __builtin_amdgcn_global_load_lds(                                      \
      (const __attribute__((address_space(1))) uint32_t*)(gp),           \
      (__attribute__((address_space(3))) uint32_t*)(lp), 16, 0, 0)

// ------ merged f32 -> bf16 convert over up to 4 segments (granule = 4) ------
__global__ void cvt4_kernel(const float* __restrict__ s0, uint16_t* __restrict__ d0, int n0,
                            const float* __restrict__ s1, uint16_t* __restrict__ d1, int n1,
                            const float* __restrict__ s2, uint16_t* __restrict__ d2, int n2,
                            const float* __restrict__ s3, uint16_t* __restrict__ d3, int n3,
                            const int* __restrict__ msk2, const int* __restrict__ msk3) {
  int e = (blockIdx.x * blockDim.x + threadIdx.x) * 4;
  const float* s;
  uint16_t* d;
  const int* msk = nullptr;
  if (e < n0) { s = s0 + e; d = d0 + e; }
  else if ((e -= n0) < n1) { s = s1 + e; d = d1 + e; }
  else if ((e -= n1) < n2) { s = s2 + e; d = d2 + e; msk = msk2; }
  else if ((e -= n2) < n3) { s = s3 + e; d = d3 + e; msk = msk3; }
  else return;
  if (msk) {
    int row = (e >> 10) & 1023, b = e >> 20;   // 1024 elems/row, 1M elems/batch
    int need = (read_len(msk, b) + 127) & ~127;
    if (row >= need) return;
  }
  const float4 v = *reinterpret_cast<const float4*>(s);
  ushort4 o;
  o.x = f2bf(v.x); o.y = f2bf(v.y); o.z = f2bf(v.z); o.w = f2bf(v.w);
  *reinterpret_cast<ushort4*>(d) = o;
}

// -------- Fused NT GEMM: Q = fr@wq^T+bq (scaled), KV = en@wkv^T+bkv --------
// 1536 blocks, balanced XCD mapping (r11), length early-exit (r10).
// ADIR=true (fast path): A fragments loaded DIRECTLY global->regs from
//   pre-converted bf16 (wave-private rows; lanes {lg,l15 fixed} hit one
//   contiguous 64B chunk/row -> coalesced, L2-resident). B via global_load_lds.
//   LDS = B only (32KB) -> 3-4 blocks/CU. A regs ping-pong one tile ahead.
// ADIR=false (fallback, small ws): r12's f32 reg-stage + LDS path.
template <bool ADIR>
__global__ __launch_bounds__(256) void gemm_fused(
    const float* __restrict__ frF, const float* __restrict__ enF,
    const uint16_t* __restrict__ frB, const uint16_t* __restrict__ enB,
    const uint16_t* __restrict__ wq, const uint16_t* __restrict__ wkv,
    const float* __restrict__ bq, const float* __restrict__ bkv,
    const int* __restrict__ l_en_p, const int* __restrict__ l_fr_p,
    uint16_t* __restrict__ Qb,       // [B,H,S,DH] bf16, pre-scaled
    uint16_t* __restrict__ Kb,       // [B,H,S,DH] bf16
    uint16_t* __restrict__ Vb) {     // [B,H,DH,S] bf16
  __shared__ __attribute__((aligned(16))) uint16_t Bs[2][128 * 64];
  __shared__ __attribute__((aligned(16))) uint16_t As[2][ADIR ? 8 : 128 * 64];
  const int t = threadIdx.x;
  const int lane = t & 63;
  const int w = t >> 6;
  const int wm = w >> 1, wn = w & 1;
  const int l15 = lane & 15, lg = lane >> 4;

  const int orig = blockIdx.x;                 // 1536 = 8 xcd * 192 slots
  const int xcd = orig & 7;
  const int slot = orig >> 3;                  // 0..191
  const bool isQ = slot < 64;
  int b, bn;
  if (isQ) { b = slot >> 3; bn = (slot & 7) * 128; }
  else { int s2 = slot - 64; b = s2 >> 4; bn = (s2 & 15) * 128; }
  const int i = (xcd - b) & 7;                 // m-tile index within batch
  const int bm = b * 1024 + i * 128;

  const int need = isQ ? read_len(l_fr_p, b) : read_len(l_en_p, b);
  if (i * 128 >= need) return;

  const uint16_t* Bw = isQ ? wq : wkv;
  const float* bias = isQ ? bq : bkv;
  const float scale = isQ ? 0.03125f : 1.0f;
  const uint16_t* Ab = isQ ? frB : enB;
  const float* Af = isQ ? frF : enF;

  f32x4 acc[4][4];
#pragma unroll
  for (int ii = 0; ii < 4; ++ii)
#pragma unroll
    for (int j = 0; j < 4; ++j) acc[ii][j] = (f32x4){0.f, 0.f, 0.f, 0.f};

  auto stageB = [&](int buf, int kt) {
#pragma unroll
    for (int ii = 0; ii < 4; ++ii) {
      int g = t + 256 * ii;           // LDS slot granule (16B units)
      int L = g ^ ((g >> 3) & 7);     // logical granule it must hold
      int row = L >> 3, k8 = L & 7;
      GLDS16(Bw + (size_t)(bn + row) * 1024 + kt + k8 * 8, &Bs[buf][g * 8]);
    }
  };
  auto loadBf = [&](int buf, int ks, bf16x8* bf) {
    const int kb = ks * 64 + lg * 16;
#pragma unroll
    for (int nf = 0; nf < 4; ++nf) {
      int row = wn * 64 + nf * 16 + l15;
      int byte = (row * 128 + kb) ^ ((row & 7) << 4);
      bf[nf] = *reinterpret_cast<const bf16x8*>(
          reinterpret_cast<const char*>(Bs[buf]) + byte);
    }
  };

  if (ADIR) {
    // ---- A-direct-register path ----
    const uint16_t* Arow = Ab + (size_t)(bm + wm * 64 + l15) * 1024 + lg * 8;
    bf16x8 a0[8], a1[8];  // [ks*4+mf], ping-pong across K-tiles
    auto loadA = [&](bf16x8* dst, int kt) {
#pragma unroll
      for (int ks = 0; ks < 2; ++ks)
#pragma unroll
        for (int mf = 0; mf < 4; ++mf)
          dst[ks * 4 + mf] = *reinterpret_cast<const bf16x8*>(
              Arow + (size_t)mf * 16 * 1024 + kt + ks * 32);
    };
    auto computeR = [&](const bf16x8* afr, int buf) {
#pragma unroll
      for (int ks = 0; ks < 2; ++ks) {
        bf16x8 bf[4];
        loadBf(buf, ks, bf);
#pragma unroll
        for (int mf = 0; mf < 4; ++mf)
#pragma unroll
          for (int nf = 0; nf < 4; ++nf)
            acc[mf][nf] = __builtin_amdgcn_mfma_f32_16x16x32_bf16(
                afr[ks * 4 + mf], bf[nf], acc[mf][nf], 0, 0, 0);
      }
    };

    loadA(a0, 0);
    stageB(0, 0);
    __syncthreads();
    for (int t2 = 0; t2 < 8; ++t2) {
      const int tt = t2 * 2;
      if (tt < 15) { stageB(1, (tt + 1) * 64); loadA(a1, (tt + 1) * 64); }
      computeR(a0, 0);
      __syncthreads();
      if (tt + 2 <= 15) { stageB(0, (tt + 2) * 64); loadA(a0, (tt + 2) * 64); }
      computeR(a1, 1);
      __syncthreads();
    }
  } else {
    // ---- fallback: f32 A reg-staged through LDS (r12 path) ----
    float4 ar0[4], ar1[4];
    auto loadA_f32 = [&](int kt) {
#pragma unroll
      for (int ii = 0; ii < 4; ++ii) {
        int L = t + 256 * ii;
        int row = L >> 3, k8 = L & 7;
        const float* src = Af + (size_t)(bm + row) * 1024 + kt + k8 * 8;
        ar0[ii] = *reinterpret_cast<const float4*>(src);
        ar1[ii] = *reinterpret_cast<const float4*>(src + 4);
      }
    };
    auto writeA = [&](int buf) {
#pragma unroll
      for (int ii = 0; ii < 4; ++ii) {
        int L = t + 256 * ii;
        int row = L >> 3, k8 = L & 7;
        ushortx8 o;
        o[0] = f2bf(ar0[ii].x); o[1] = f2bf(ar0[ii].y);
        o[2] = f2bf(ar0[ii].z); o[3] = f2bf(ar0[ii].w);
        o[4] = f2bf(ar1[ii].x); o[5] = f2bf(ar1[ii].y);
        o[6] = f2bf(ar1[ii].z); o[7] = f2bf(ar1[ii].w);
        int byte = (row * 128 + k8 * 16) ^ ((row & 7) << 4);
        *reinterpret_cast<ushortx8*>(reinterpret_cast<char*>(As[buf]) + byte) = o;
      }
    };
    auto compute = [&](int buf) {
#pragma unroll
      for (int ks = 0; ks < 2; ++ks) {
        const int kb = ks * 64 + lg * 16;
        bf16x8 af[4], bf[4];
#pragma unroll
        for (int mf = 0; mf < 4; ++mf) {
          int row = wm * 64 + mf * 16 + l15;
          int byte = (row * 128 + kb) ^ ((row & 7) << 4);
          af[mf] = *reinterpret_cast<const bf16x8*>(
              reinterpret_cast<const char*>(As[buf]) + byte);
        }
        loadBf(buf, ks, bf);
#pragma unroll
        for (int mf = 0; mf < 4; ++mf)
#pragma unroll
          for (int nf = 0; nf < 4; ++nf)
            acc[mf][nf] = __builtin_amdgcn_mfma_f32_16x16x32_bf16(
                af[mf], bf[nf], acc[mf][nf], 0, 0, 0);
      }
    };
    loadA_f32(0);
    stageB(0, 0);
    writeA(0);
    __syncthreads();
#pragma unroll 2
    for (int tt = 0; tt < 16; ++tt) {
      const int cur = tt & 1;
      const int ktn = (tt + 1) * 64;
      if (tt < 15) { stageB(cur ^ 1, ktn); loadA_f32(ktn); }
      compute(cur);
      if (tt < 15) writeA(cur ^ 1);
      __syncthreads();
    }
  }

  // Epilogue: add bias, scale, scatter bf16 to attention layouts.
#pragma unroll
  for (int mf = 0; mf < 4; ++mf) {
#pragma unroll
    for (int nf = 0; nf < 4; ++nf) {
      int n = bn + wn * 64 + nf * 16 + l15;
      float bv = bias[n];
#pragma unroll
      for (int r = 0; r < 4; ++r) {
        int m = bm + wm * 64 + mf * 16 + lg * 4 + r;
        float v = (acc[mf][nf][r] + bv) * scale;
        uint16_t o = f2bf(v);
        int bb = m >> 10, s = m & 1023;
        if (isQ) {
          int h = n >> 6, d = n & 63;
          Qb[((((bb * 16 + h) << 10) | s) << 6) | d] = o;
        } else if (n < 1024) {
          int h = n >> 6, d = n & 63;
          Kb[((((bb * 16 + h) << 10) | s) << 6) | d] = o;
        } else {
          int n2 = n - 1024;
          int h = n2 >> 6, d = n2 & 63;
          Vb[((((bb * 16 + h) << 6) | d) << 10) | s] = o;
        }
      }
    }
  }
}

// ---------------- Flash attention (unchanged from r12) ----------------
__global__ __launch_bounds__(512) void attn_kernel(
    const uint16_t* __restrict__ Qb,  // [B,H,S,DH] bf16, pre-scaled
    const uint16_t* __restrict__ Kb,  // [B,H,S,DH] bf16
    const uint16_t* __restrict__ Vt,  // [B,H,DH,S] bf16
    const int* __restrict__ l_en_p, const int* __restrict__ l_fr_p,
    float* __restrict__ out) {        // [B,S,D] f32
  __shared__ __attribute__((aligned(16))) uint16_t Ks[2][64 * 64];
  __shared__ __attribute__((aligned(16))) uint16_t Vs[2][64 * 64];
  __shared__ __attribute__((aligned(16))) bf16_t Ps[8][16][72];
  const int t = threadIdx.x;
  const int lane = t & 63, w = t >> 6;          // w in 0..7
  const int l15 = lane & 15, lg = lane >> 4;
  const int orig = blockIdx.x;
  const int xcd = orig & 7;
  const int slot = orig >> 3;                  // 0..127
  const int b = slot >> 4;
  const int rest = slot & 15;
  const int h = xcd + 8 * (rest >> 3);
  const int q0 = (rest & 7) << 7;              // 128-row tile
  const int bh = b * 16 + h;
  const int len_en = read_len(l_en_p, b);
  const int len_fr = read_len(l_fr_p, b);

  if (q0 >= len_fr) {
    for (int i = t; i < 128 * 64; i += 512) {
      int rr = i >> 6, cc = i & 63;
      out[(size_t)(b * 1024 + q0 + rr) * 1024 + h * 64 + cc] = 0.f;
    }
    return;
  }

  const uint16_t* qbase =
      Qb + ((size_t)bh * 1024 + q0 + w * 16 + l15) * 64 + lg * 8;
  const bf16x8 aq0 = *reinterpret_cast<const bf16x8*>(qbase);
  const bf16x8 aq1 = *reinterpret_cast<const bf16x8*>(qbase + 32);

  float mrow[4], lrow[4];
  f32x4 oacc[4];
#pragma unroll
  for (int r = 0; r < 4; ++r) { mrow[r] = -1e30f; lrow[r] = 0.f; }
#pragma unroll
  for (int df = 0; df < 4; ++df) oacc[df] = (f32x4){0.f, 0.f, 0.f, 0.f};

  auto stage = [&](int buf, int j0) {
    int g = t;
    int L = g ^ ((g >> 3) & 7);
    int row = L >> 3, k8 = L & 7;
    GLDS16(Kb + ((size_t)bh * 1024 + j0 + row) * 64 + k8 * 8, &Ks[buf][g * 8]);
    GLDS16(Vt + ((size_t)bh * 64 + row) * 1024 + j0 + k8 * 8, &Vs[buf][g * 8]);
  };

  const int ntiles = (len_en + 63) >> 6;
  stage(0, 0);
  __syncthreads();

  for (int tt = 0; tt < ntiles; ++tt) {
    const int cur = tt & 1;
    const int j0 = tt * 64;
    if (tt + 1 < ntiles) stage(cur ^ 1, (tt + 1) * 64);

    f32x4 sc[4];
#pragma unroll
    for (int nf = 0; nf < 4; ++nf) sc[nf] = (f32x4){0.f, 0.f, 0.f, 0.f};
#pragma unroll
    for (int ks = 0; ks < 2; ++ks) {
      const bf16x8 aq = ks ? aq1 : aq0;
      const int kb = ks * 64 + lg * 16;
#pragma unroll
      for (int nf = 0; nf < 4; ++nf) {
        int row = nf * 16 + l15;
        int byte = (row * 128 + kb) ^ ((row & 7) << 4);
        bf16x8 bk = *reinterpret_cast<const bf16x8*>(
            reinterpret_cast<const char*>(Ks[cur]) + byte);
        sc[nf] = __builtin_amdgcn_mfma_f32_16x16x32_bf16(aq, bk, sc[nf], 0, 0, 0);
      }
    }
#pragma unroll
    for (int nf = 0; nf < 4; ++nf) {
      int col = j0 + nf * 16 + l15;
      if (col >= len_en) sc[nf] = (f32x4){-1e30f, -1e30f, -1e30f, -1e30f};
    }
    float tm[4];
#pragma unroll
    for (int r = 0; r < 4; ++r)
      tm[r] = fmaxf(fmaxf(sc[0][r], sc[1][r]), fmaxf(sc[2][r], sc[3][r]));
#pragma unroll
    for (int off = 1; off < 16; off <<= 1)
#pragma unroll
      for (int r = 0; r < 4; ++r) tm[r] = fmaxf(tm[r], __shfl_xor(tm[r], off));

    bool small = (tm[0] <= mrow[0] + 8.f) && (tm[1] <= mrow[1] + 8.f) &&
                 (tm[2] <= mrow[2] + 8.f) && (tm[3] <= mrow[3] + 8.f);
    if (!__all(small)) {
      float fac[4];
#pragma unroll
      for (int r = 0; r < 4; ++r) {
        float mn = fmaxf(mrow[r], tm[r]);
        fac[r] = __expf(mrow[r] - mn);
        mrow[r] = mn;
      }
#pragma unroll
      for (int r = 0; r < 4; ++r) lrow[r] *= fac[r];
#pragma unroll
      for (int df = 0; df < 4; ++df)
#pragma unroll
        for (int r = 0; r < 4; ++r) oacc[df][r] *= fac[r];
    }
    float ps[4] = {0.f, 0.f, 0.f, 0.f};
#pragma unroll
    for (int nf = 0; nf < 4; ++nf)
#pragma unroll
      for (int r = 0; r < 4; ++r) {
        float p = __expf(sc[nf][r] - mrow[r]);
        ps[r] += p;
        Ps[w][lg * 4 + r][nf * 16 + l15] = (bf16_t)p;
      }
#pragma unroll
    for (int off = 1; off < 16; off <<= 1)
#pragma unroll
      for (int r = 0; r < 4; ++r) ps[r] += __shfl_xor(ps[r], off);
#pragma unroll
    for (int r = 0; r < 4; ++r) lrow[r] += ps[r];

#pragma unroll
    for (int ks = 0; ks < 2; ++ks) {
      const bf16x8 pa = *reinterpret_cast<const bf16x8*>(
          &Ps[w][l15][0] + ks * 32 + lg * 8);
#pragma unroll
      for (int df = 0; df < 4; ++df) {
        int row = df * 16 + l15;
        int byte = (row * 128 + ks * 64 + lg * 16) ^ ((row & 7) << 4);
        bf16x8 bv = *reinterpret_cast<const bf16x8*>(
            reinterpret_cast<const char*>(Vs[cur]) + byte);
        oacc[df] = __builtin_amdgcn_mfma_f32_16x16x32_bf16(pa, bv, oacc[df], 0, 0, 0);
      }
    }
    __syncthreads();
  }

#pragma unroll
  for (int df = 0; df < 4; ++df)
#pragma unroll
    for (int r = 0; r < 4; ++r) {
      int q = q0 + w * 16 + lg * 4 + r;
      float inv = (q < len_fr && lrow[r] > 0.f) ? 1.0f / lrow[r] : 0.f;
      out[(size_t)(b * 1024 + q) * 1024 + h * 64 + df * 16 + l15] =
          oacc[df][r] * inv;
    }
}

// ---------------- launch ----------------
extern "C" void kernel_launch(void* const* d_in, const int* in_sizes, int n_in,
                              void* d_out, int out_size, void* d_ws,
                              size_t ws_size, hipStream_t stream) {
  const float* en = (const float*)d_in[0];
  const float* fr = (const float*)d_in[1];
  const int* l_en = (const int*)d_in[2];
  const int* l_fr = (const int*)d_in[3];
  const float* wq = (const float*)d_in[4];
  const float* bq = (const float*)d_in[5];
  const float* wkv = (const float*)d_in[6];
  const float* bkv = (const float*)d_in[7];
  float* out = (float*)d_out;  // output dtype is FLOAT32

  // Workspace layout (bytes):
  // wq_bf 0..2M | wkv_bf 2M..6M | Qbuf 6M..23M | Kbuf 23M..40M | Vtbuf 40M..56.6M
  // [fast path] fr_bf 56.6M..73.4M | en_bf 73.4M..90.2M
  char* ws = (char*)d_ws;
  uint16_t* wq_bf = (uint16_t*)(ws);
  uint16_t* wkv_bf = (uint16_t*)(ws + 2097152);
  uint16_t* Qbuf = (uint16_t*)(ws + 6291456);
  uint16_t* Kbuf = (uint16_t*)(ws + 23068672);
  uint16_t* Vtbuf = (uint16_t*)(ws + 39845888);
  uint16_t* fr_bf = (uint16_t*)(ws + 56623104);
  uint16_t* en_bf = (uint16_t*)(ws + 73400320);
  const bool pre = ws_size >= 90177536ull;

  if (pre) {
    cvt4_kernel<<<19456, 256, 0, stream>>>(wq, wq_bf, 1048576,
                                           wkv, wkv_bf, 2097152,
                                           fr, fr_bf, 8388608,
                                           en, en_bf, 8388608,
                                           l_fr, l_en);
    gemm_fused<true><<<1536, 256, 0, stream>>>(nullptr, nullptr, fr_bf, en_bf,
                                               wq_bf, wkv_bf, bq, bkv,
                                               l_en, l_fr, Qbuf, Kbuf, Vtbuf);
  } else {
    cvt4_kernel<<<3072, 256, 0, stream>>>(wq, wq_bf, 1048576,
                                          wkv, wkv_bf, 2097152,
                                          nullptr, nullptr, 0,
                                          nullptr, nullptr, 0,
                                          nullptr, nullptr);
    gemm_fused<false><<<1536, 256, 0, stream>>>(fr, en, nullptr, nullptr,
                                                wq_bf, wkv_bf, bq, bkv,
                                                l_en, l_fr, Qbuf, Kbuf, Vtbuf);
  }

  attn_kernel<<<1024, 512, 0, stream>>>(Qbuf, Kbuf, Vtbuf, l_en, l_fr, out);
}

// Round 15
// 115.508 us; speedup vs baseline: 1.2732x; 1.2732x over previous
//
#include <hip/hip_runtime.h>
#include <hip/hip_bf16.h>
#include <stdint.h>

// Problem constants: B=8, S=1024, D=1024, H=16, DH=64
typedef __bf16 bf16_t;
typedef bf16_t bf16x8 __attribute__((ext_vector_type(8)));
typedef float f32x4 __attribute__((ext_vector_type(4)));
typedef unsigned short ushortx8 __attribute__((ext_vector_type(8)));

__device__ __forceinline__ uint16_t f2bf(float f) {
  uint32_t u = __float_as_uint(f);
  uint32_t r = u + 0x7FFFu + ((u >> 16) & 1u);  // RNE
  return (uint16_t)(r >> 16);
}

__device__ __forceinline__ int read_len(const int* __restrict__ p, int b) {
  bool is64 = (p[1] == 0) | (p[3] == 0) | (p[5] == 0) | (p[7] == 0);
  return is64 ? p[2 * b] : p[b];
}

#define GLDS16(gp, lp)                                                   \
  __builtin_amdgcn_global_load_lds(                                      \
      (const __attribute__((address_space(1))) uint32_t*)(gp),           \
      (__attribute__((address_space(3))) uint32_t*)(lp), 16, 0, 0)

// ------ merged f32 -> bf16 convert over up to 4 segments (granule = 4) ------
__global__ void cvt4_kernel(const float* __restrict__ s0, uint16_t* __restrict__ d0, int n0,
                            const float* __restrict__ s1, uint16_t* __restrict__ d1, int n1,
                            const float* __restrict__ s2, uint16_t* __restrict__ d2, int n2,
                            const float* __restrict__ s3, uint16_t* __restrict__ d3, int n3,
                            const int* __restrict__ msk2, const int* __restrict__ msk3) {
  int e = (blockIdx.x * blockDim.x + threadIdx.x) * 4;
  const float* s;
  uint16_t* d;
  const int* msk = nullptr;
  if (e < n0) { s = s0 + e; d = d0 + e; }
  else if ((e -= n0) < n1) { s = s1 + e; d = d1 + e; }
  else if ((e -= n1) < n2) { s = s2 + e; d = d2 + e; msk = msk2; }
  else if ((e -= n2) < n3) { s = s3 + e; d = d3 + e; msk = msk3; }
  else return;
  if (msk) {
    int row = (e >> 10) & 1023, b = e >> 20;   // 1024 elems/row, 1M elems/batch
    int need = (read_len(msk, b) + 127) & ~127;
    if (row >= need) return;
  }
  const float4 v = *reinterpret_cast<const float4*>(s);
  ushort4 o;
  o.x = f2bf(v.x); o.y = f2bf(v.y); o.z = f2bf(v.z); o.w = f2bf(v.w);
  *reinterpret_cast<ushort4*>(d) = o;
}

// -------- Fused NT GEMM: Q = fr@wq^T+bq (scaled), KV = en@wkv^T+bkv --------
// 1536 blocks, balanced XCD mapping (r11), length early-exit (r10).
// ABF16 (fast path): A+B bf16 via global_load_lds. Counted-vmcnt pipeline
//   (T4/m201 discipline): B weights 3-deep LDS ring (loads span 2 iters),
//   A 2-deep; raw s_barrier + `s_waitcnt vmcnt(4)` (never 0 mid-loop).
//   All LDS writes are vmcnt-tracked GLDS; ds_reads consumed by MFMAs
//   pre-barrier; sched_barrier(0) after each barrier (rule #18).
// !ABF16 fallback: r12's f32 reg-stage + syncthreads 2-phase (unchanged).
template <bool ABF16>
__global__ __launch_bounds__(256) void gemm_fused(
    const float* __restrict__ frF, const float* __restrict__ enF,
    const uint16_t* __restrict__ frB, const uint16_t* __restrict__ enB,
    const uint16_t* __restrict__ wq, const uint16_t* __restrict__ wkv,
    const float* __restrict__ bq, const float* __restrict__ bkv,
    const int* __restrict__ l_en_p, const int* __restrict__ l_fr_p,
    uint16_t* __restrict__ Qb,       // [B,H,S,DH] bf16, pre-scaled
    uint16_t* __restrict__ Kb,       // [B,H,S,DH] bf16
    uint16_t* __restrict__ Vb) {     // [B,H,DH,S] bf16
  __shared__ __attribute__((aligned(16))) uint16_t As[2][128 * 64];
  __shared__ __attribute__((aligned(16))) uint16_t Bs[ABF16 ? 3 : 2][128 * 64];
  const int t = threadIdx.x;
  const int lane = t & 63;
  const int w = t >> 6;
  const int wm = w >> 1, wn = w & 1;
  const int l15 = lane & 15, lg = lane >> 4;

  const int orig = blockIdx.x;                 // 1536 = 8 xcd * 192 slots
  const int xcd = orig & 7;
  const int slot = orig >> 3;                  // 0..191
  const bool isQ = slot < 64;
  int b, bn;
  if (isQ) { b = slot >> 3; bn = (slot & 7) * 128; }
  else { int s2 = slot - 64; b = s2 >> 4; bn = (s2 & 15) * 128; }
  const int i = (xcd - b) & 7;                 // m-tile index within batch
  const int bm = b * 1024 + i * 128;

  const int need = isQ ? read_len(l_fr_p, b) : read_len(l_en_p, b);
  if (i * 128 >= need) return;

  const uint16_t* Bw = isQ ? wq : wkv;
  const float* bias = isQ ? bq : bkv;
  const float scale = isQ ? 0.03125f : 1.0f;
  const uint16_t* Ab = isQ ? frB : enB;
  const float* Af = isQ ? frF : enF;

  f32x4 acc[4][4];
#pragma unroll
  for (int ii = 0; ii < 4; ++ii)
#pragma unroll
    for (int j = 0; j < 4; ++j) acc[ii][j] = (f32x4){0.f, 0.f, 0.f, 0.f};

  auto stageB = [&](int buf, int kt) {
#pragma unroll
    for (int ii = 0; ii < 4; ++ii) {
      int g = t + 256 * ii;           // LDS slot granule (16B units)
      int L = g ^ ((g >> 3) & 7);     // logical granule it must hold
      int row = L >> 3, k8 = L & 7;
      GLDS16(Bw + (size_t)(bn + row) * 1024 + kt + k8 * 8, &Bs[buf][g * 8]);
    }
  };
  auto stageA_bf = [&](int buf, int kt) {
#pragma unroll
    for (int ii = 0; ii < 4; ++ii) {
      int g = t + 256 * ii;
      int L = g ^ ((g >> 3) & 7);
      int row = L >> 3, k8 = L & 7;
      GLDS16(Ab + (size_t)(bm + row) * 1024 + kt + k8 * 8, &As[buf][g * 8]);
    }
  };
  auto computeAB = [&](int bufA, int bufB) {
#pragma unroll
    for (int ks = 0; ks < 2; ++ks) {
      const int kb = ks * 64 + lg * 16;  // byte offset within a 128B row
      bf16x8 af[4], bf[4];
#pragma unroll
      for (int mf = 0; mf < 4; ++mf) {
        int row = wm * 64 + mf * 16 + l15;
        int byte = (row * 128 + kb) ^ ((row & 7) << 4);
        af[mf] = *reinterpret_cast<const bf16x8*>(
            reinterpret_cast<const char*>(As[bufA]) + byte);
      }
#pragma unroll
      for (int nf = 0; nf < 4; ++nf) {
        int row = wn * 64 + nf * 16 + l15;
        int byte = (row * 128 + kb) ^ ((row & 7) << 4);
        bf[nf] = *reinterpret_cast<const bf16x8*>(
            reinterpret_cast<const char*>(Bs[bufB]) + byte);
      }
#pragma unroll
      for (int mf = 0; mf < 4; ++mf)
#pragma unroll
        for (int nf = 0; nf < 4; ++nf)
          acc[mf][nf] = __builtin_amdgcn_mfma_f32_16x16x32_bf16(
              af[mf], bf[nf], acc[mf][nf], 0, 0, 0);
    }
  };

  if (ABF16) {
    // ---- counted-vmcnt pipeline: A 2-deep, B 3-deep ----
    stageA_bf(0, 0);   // 4 loads
    stageB(0, 0);      // 4 loads
    stageB(1, 64);     // 4 loads (stays in flight across the wait)
    asm volatile("s_waitcnt vmcnt(4)" ::: "memory");  // A0,B0 done
    __builtin_amdgcn_s_barrier();
    __builtin_amdgcn_sched_barrier(0);
    int bA = 0, bB = 0;
    for (int tt = 0; tt < 16; ++tt) {
      if (tt + 1 < 16) stageA_bf(bA ^ 1, (tt + 1) * 64);          // 4 loads
      if (tt + 2 < 16) stageB(bB >= 1 ? bB - 1 : bB + 2, (tt + 2) * 64); // 4
      computeAB(bA, bB);
      if (tt < 15) {
        // Need A(t+1),B(t+1) complete; leave B(t+2)'s 4 loads in flight.
        if (tt < 14) asm volatile("s_waitcnt vmcnt(4)" ::: "memory");
        else         asm volatile("s_waitcnt vmcnt(0)" ::: "memory");
        __builtin_amdgcn_s_barrier();
        __builtin_amdgcn_sched_barrier(0);
      }
      bA ^= 1;
      bB = (bB == 2) ? 0 : bB + 1;
    }
  } else {
    // ---- fallback: f32 A reg-staged, __syncthreads 2-phase (r12) ----
    float4 ar0[4], ar1[4];
    auto loadA_f32 = [&](int kt) {
#pragma unroll
      for (int ii = 0; ii < 4; ++ii) {
        int L = t + 256 * ii;
        int row = L >> 3, k8 = L & 7;
        const float* src = Af + (size_t)(bm + row) * 1024 + kt + k8 * 8;
        ar0[ii] = *reinterpret_cast<const float4*>(src);
        ar1[ii] = *reinterpret_cast<const float4*>(src + 4);
      }
    };
    auto writeA = [&](int buf) {
#pragma unroll
      for (int ii = 0; ii < 4; ++ii) {
        int L = t + 256 * ii;
        int row = L >> 3, k8 = L & 7;
        ushortx8 o;
        o[0] = f2bf(ar0[ii].x); o[1] = f2bf(ar0[ii].y);
        o[2] = f2bf(ar0[ii].z); o[3] = f2bf(ar0[ii].w);
        o[4] = f2bf(ar1[ii].x); o[5] = f2bf(ar1[ii].y);
        o[6] = f2bf(ar1[ii].z); o[7] = f2bf(ar1[ii].w);
        int byte = (row * 128 + k8 * 16) ^ ((row & 7) << 4);
        *reinterpret_cast<ushortx8*>(reinterpret_cast<char*>(As[buf]) + byte) = o;
      }
    };
    loadA_f32(0);
    stageB(0, 0);
    writeA(0);
    __syncthreads();
#pragma unroll 2
    for (int tt = 0; tt < 16; ++tt) {
      const int cur = tt & 1;
      const int ktn = (tt + 1) * 64;
      if (tt < 15) { stageB(cur ^ 1, ktn); loadA_f32(ktn); }
      computeAB(cur, cur);
      if (tt < 15) writeA(cur ^ 1);
      __syncthreads();
    }
  }

  // Epilogue: add bias, scale, scatter bf16 to attention layouts.
#pragma unroll
  for (int mf = 0; mf < 4; ++mf) {
#pragma unroll
    for (int nf = 0; nf < 4; ++nf) {
      int n = bn + wn * 64 + nf * 16 + l15;
      float bv = bias[n];
#pragma unroll
      for (int r = 0; r < 4; ++r) {
        int m = bm + wm * 64 + mf * 16 + lg * 4 + r;
        float v = (acc[mf][nf][r] + bv) * scale;
        uint16_t o = f2bf(v);
        int bb = m >> 10, s = m & 1023;
        if (isQ) {
          int h = n >> 6, d = n & 63;
          Qb[((((bb * 16 + h) << 10) | s) << 6) | d] = o;
        } else if (n < 1024) {
          int h = n >> 6, d = n & 63;
          Kb[((((bb * 16 + h) << 10) | s) << 6) | d] = o;
        } else {
          int n2 = n - 1024;
          int h = n2 >> 6, d = n2 & 63;
          Vb[((((bb * 16 + h) << 6) | d) << 10) | s] = o;
        }
      }
    }
  }
}

// ---------------- Flash attention (r12 + T5 setprio) ----------------
// 1024 blocks x 512 threads (8 waves), QBLK=128, K/V 2-phase dbuf,
// defer-max (THR=8), balanced XCD mapping (XCD = h&7).
__global__ __launch_bounds__(512) void attn_kernel(
    const uint16_t* __restrict__ Qb,  // [B,H,S,DH] bf16, pre-scaled
    const uint16_t* __restrict__ Kb,  // [B,H,S,DH] bf16
    const uint16_t* __restrict__ Vt,  // [B,H,DH,S] bf16
    const int* __restrict__ l_en_p, const int* __restrict__ l_fr_p,
    float* __restrict__ out) {        // [B,S,D] f32
  __shared__ __attribute__((aligned(16))) uint16_t Ks[2][64 * 64];
  __shared__ __attribute__((aligned(16))) uint16_t Vs[2][64 * 64];
  __shared__ __attribute__((aligned(16))) bf16_t Ps[8][16][72];
  const int t = threadIdx.x;
  const int lane = t & 63, w = t >> 6;          // w in 0..7
  const int l15 = lane & 15, lg = lane >> 4;
  const int orig = blockIdx.x;
  const int xcd = orig & 7;
  const int slot = orig >> 3;                  // 0..127
  const int b = slot >> 4;
  const int rest = slot & 15;
  const int h = xcd + 8 * (rest >> 3);
  const int q0 = (rest & 7) << 7;              // 128-row tile
  const int bh = b * 16 + h;
  const int len_en = read_len(l_en_p, b);
  const int len_fr = read_len(l_fr_p, b);

  if (q0 >= len_fr) {
    for (int i = t; i < 128 * 64; i += 512) {
      int rr = i >> 6, cc = i & 63;
      out[(size_t)(b * 1024 + q0 + rr) * 1024 + h * 64 + cc] = 0.f;
    }
    return;
  }

  const uint16_t* qbase =
      Qb + ((size_t)bh * 1024 + q0 + w * 16 + l15) * 64 + lg * 8;
  const bf16x8 aq0 = *reinterpret_cast<const bf16x8*>(qbase);
  const bf16x8 aq1 = *reinterpret_cast<const bf16x8*>(qbase + 32);

  float mrow[4], lrow[4];
  f32x4 oacc[4];
#pragma unroll
  for (int r = 0; r < 4; ++r) { mrow[r] = -1e30f; lrow[r] = 0.f; }
#pragma unroll
  for (int df = 0; df < 4; ++df) oacc[df] = (f32x4){0.f, 0.f, 0.f, 0.f};

  auto stage = [&](int buf, int j0) {
    int g = t;
    int L = g ^ ((g >> 3) & 7);
    int row = L >> 3, k8 = L & 7;
    GLDS16(Kb + ((size_t)bh * 1024 + j0 + row) * 64 + k8 * 8, &Ks[buf][g * 8]);
    GLDS16(Vt + ((size_t)bh * 64 + row) * 1024 + j0 + k8 * 8, &Vs[buf][g * 8]);
  };

  const int ntiles = (len_en + 63) >> 6;
  stage(0, 0);
  __syncthreads();

  for (int tt = 0; tt < ntiles; ++tt) {
    const int cur = tt & 1;
    const int j0 = tt * 64;
    if (tt + 1 < ntiles) stage(cur ^ 1, (tt + 1) * 64);

    f32x4 sc[4];
#pragma unroll
    for (int nf = 0; nf < 4; ++nf) sc[nf] = (f32x4){0.f, 0.f, 0.f, 0.f};
    __builtin_amdgcn_s_setprio(1);
#pragma unroll
    for (int ks = 0; ks < 2; ++ks) {
      const bf16x8 aq = ks ? aq1 : aq0;
      const int kb = ks * 64 + lg * 16;
#pragma unroll
      for (int nf = 0; nf < 4; ++nf) {
        int row = nf * 16 + l15;
        int byte = (row * 128 + kb) ^ ((row & 7) << 4);
        bf16x8 bk = *reinterpret_cast<const bf16x8*>(
            reinterpret_cast<const char*>(Ks[cur]) + byte);
        sc[nf] = __builtin_amdgcn_mfma_f32_16x16x32_bf16(aq, bk, sc[nf], 0, 0, 0);
      }
    }
    __builtin_amdgcn_s_setprio(0);
#pragma unroll
    for (int nf = 0; nf < 4; ++nf) {
      int col = j0 + nf * 16 + l15;
      if (col >= len_en) sc[nf] = (f32x4){-1e30f, -1e30f, -1e30f, -1e30f};
    }
    float tm[4];
#pragma unroll
    for (int r = 0; r < 4; ++r)
      tm[r] = fmaxf(fmaxf(sc[0][r], sc[1][r]), fmaxf(sc[2][r], sc[3][r]));
#pragma unroll
    for (int off = 1; off < 16; off <<= 1)
#pragma unroll
      for (int r = 0; r < 4; ++r) tm[r] = fmaxf(tm[r], __shfl_xor(tm[r], off));

    bool small = (tm[0] <= mrow[0] + 8.f) && (tm[1] <= mrow[1] + 8.f) &&
                 (tm[2] <= mrow[2] + 8.f) && (tm[3] <= mrow[3] + 8.f);
    if (!__all(small)) {
      float fac[4];
#pragma unroll
      for (int r = 0; r < 4; ++r) {
        float mn = fmaxf(mrow[r], tm[r]);
        fac[r] = __expf(mrow[r] - mn);
        mrow[r] = mn;
      }
#pragma unroll
      for (int r = 0; r < 4; ++r) lrow[r] *= fac[r];
#pragma unroll
      for (int df = 0; df < 4; ++df)
#pragma unroll
        for (int r = 0; r < 4; ++r) oacc[df][r] *= fac[r];
    }
    float ps[4] = {0.f, 0.f, 0.f, 0.f};
#pragma unroll
    for (int nf = 0; nf < 4; ++nf)
#pragma unroll
      for (int r = 0; r < 4; ++r) {
        float p = __expf(sc[nf][r] - mrow[r]);
        ps[r] += p;
        Ps[w][lg * 4 + r][nf * 16 + l15] = (bf16_t)p;
      }
#pragma unroll
    for (int off = 1; off < 16; off <<= 1)
#pragma unroll
      for (int r = 0; r < 4; ++r) ps[r] += __shfl_xor(ps[r], off);
#pragma unroll
    for (int r = 0; r < 4; ++r) lrow[r] += ps[r];

    __builtin_amdgcn_s_setprio(1);
#pragma unroll
    for (int ks = 0; ks < 2; ++ks) {
      const bf16x8 pa = *reinterpret_cast<const bf16x8*>(
          &Ps[w][l15][0] + ks * 32 + lg * 8);
#pragma unroll
      for (int df = 0; df < 4; ++df) {
        int row = df * 16 + l15;
        int byte = (row * 128 + ks * 64 + lg * 16) ^ ((row & 7) << 4);
        bf16x8 bv = *reinterpret_cast<const bf16x8*>(
            reinterpret_cast<const char*>(Vs[cur]) + byte);
        oacc[df] = __builtin_amdgcn_mfma_f32_16x16x32_bf16(pa, bv, oacc[df], 0, 0, 0);
      }
    }
    __builtin_amdgcn_s_setprio(0);
    __syncthreads();
  }

#pragma unroll
  for (int df = 0; df < 4; ++df)
#pragma unroll
    for (int r = 0; r < 4; ++r) {
      int q = q0 + w * 16 + lg * 4 + r;
      float inv = (q < len_fr && lrow[r] > 0.f) ? 1.0f / lrow[r] : 0.f;
      out[(size_t)(b * 1024 + q) * 1024 + h * 64 + df * 16 + l15] =
          oacc[df][r] * inv;
    }
}

// ---------------- launch ----------------
extern "C" void kernel_launch(void* const* d_in, const int* in_sizes, int n_in,
                              void* d_out, int out_size, void* d_ws,
                              size_t ws_size, hipStream_t stream) {
  const float* en = (const float*)d_in[0];
  const float* fr = (const float*)d_in[1];
  const int* l_en = (const int*)d_in[2];
  const int* l_fr = (const int*)d_in[3];
  const float* wq = (const float*)d_in[4];
  const float* bq = (const float*)d_in[5];
  const float* wkv = (const float*)d_in[6];
  const float* bkv = (const float*)d_in[7];
  float* out = (float*)d_out;  // output dtype is FLOAT32

  // Workspace layout (bytes):
  // wq_bf 0..2M | wkv_bf 2M..6M | Qbuf 6M..23M | Kbuf 23M..40M | Vtbuf 40M..56.6M
  // [fast path] fr_bf 56.6M..73.4M | en_bf 73.4M..90.2M
  char* ws = (char*)d_ws;
  uint16_t* wq_bf = (uint16_t*)(ws);
  uint16_t* wkv_bf = (uint16_t*)(ws + 2097152);
  uint16_t* Qbuf = (uint16_t*)(ws + 6291456);
  uint16_t* Kbuf = (uint16_t*)(ws + 23068672);
  uint16_t* Vtbuf = (uint16_t*)(ws + 39845888);
  uint16_t* fr_bf = (uint16_t*)(ws + 56623104);
  uint16_t* en_bf = (uint16_t*)(ws + 73400320);
  const bool pre = ws_size >= 90177536ull;

  if (pre) {
    cvt4_kernel<<<19456, 256, 0, stream>>>(wq, wq_bf, 1048576,
                                           wkv, wkv_bf, 2097152,
                                           fr, fr_bf, 8388608,
                                           en, en_bf, 8388608,
                                           l_fr, l_en);
    gemm_fused<true><<<1536, 256, 0, stream>>>(nullptr, nullptr, fr_bf, en_bf,
                                               wq_bf, wkv_bf, bq, bkv,
                                               l_en, l_fr, Qbuf, Kbuf, Vtbuf);
  } else {
    cvt4_kernel<<<3072, 256, 0, stream>>>(wq, wq_bf, 1048576,
                                          wkv, wkv_bf, 2097152,
                                          nullptr, nullptr, 0,
                                          nullptr, nullptr, 0,
                                          nullptr, nullptr);
    gemm_fused<false><<<1536, 256, 0, stream>>>(fr, en, nullptr, nullptr,
                                                wq_bf, wkv_bf, bq, bkv,
                                                l_en, l_fr, Qbuf, Kbuf, Vtbuf);
  }

  attn_kernel<<<1024, 512, 0, stream>>>(Qbuf, Kbuf, Vtbuf, l_en, l_fr, out);
}

// Round 16
// 115.491 us; speedup vs baseline: 1.2734x; 1.0001x over previous
//
#include <hip/hip_runtime.h>
#include <hip/hip_bf16.h>
#include <stdint.h>

// Problem constants: B=8, S=1024, D=1024, H=16, DH=64
typedef __bf16 bf16_t;
typedef bf16_t bf16x8 __attribute__((ext_vector_type(8)));
typedef float f32x4 __attribute__((ext_vector_type(4)));
typedef unsigned short ushortx8 __attribute__((ext_vector_type(8)));

__device__ __forceinline__ uint16_t f2bf(float f) {
  uint32_t u = __float_as_uint(f);
  uint32_t r = u + 0x7FFFu + ((u >> 16) & 1u);  // RNE
  return (uint16_t)(r >> 16);
}

__device__ __forceinline__ int read_len(const int* __restrict__ p, int b) {
  bool is64 = (p[1] == 0) | (p[3] == 0) | (p[5] == 0) | (p[7] == 0);
  return is64 ? p[2 * b] : p[b];
}

#define GLDS16(gp, lp)                                                   \
  __builtin_amdgcn_global_load_lds(                                      \
      (const __attribute__((address_space(1))) uint32_t*)(gp),           \
      (__attribute__((address_space(3))) uint32_t*)(lp), 16, 0, 0)

// ------ merged f32 -> bf16 convert over up to 4 segments (granule = 4) ------
__global__ void cvt4_kernel(const float* __restrict__ s0, uint16_t* __restrict__ d0, int n0,
                            const float* __restrict__ s1, uint16_t* __restrict__ d1, int n1,
                            const float* __restrict__ s2, uint16_t* __restrict__ d2, int n2,
                            const float* __restrict__ s3, uint16_t* __restrict__ d3, int n3,
                            const int* __restrict__ msk2, const int* __restrict__ msk3) {
  int e = (blockIdx.x * blockDim.x + threadIdx.x) * 4;
  const float* s;
  uint16_t* d;
  const int* msk = nullptr;
  if (e < n0) { s = s0 + e; d = d0 + e; }
  else if ((e -= n0) < n1) { s = s1 + e; d = d1 + e; }
  else if ((e -= n1) < n2) { s = s2 + e; d = d2 + e; msk = msk2; }
  else if ((e -= n2) < n3) { s = s3 + e; d = d3 + e; msk = msk3; }
  else return;
  if (msk) {
    int row = (e >> 10) & 1023, b = e >> 20;   // 1024 elems/row, 1M elems/batch
    int need = (read_len(msk, b) + 127) & ~127;
    if (row >= need) return;
  }
  const float4 v = *reinterpret_cast<const float4*>(s);
  ushort4 o;
  o.x = f2bf(v.x); o.y = f2bf(v.y); o.z = f2bf(v.z); o.w = f2bf(v.w);
  *reinterpret_cast<ushort4*>(d) = o;
}

// -------- Fused NT GEMM: Q = fr@wq^T+bq (scaled), KV = en@wkv^T+bkv --------
// 1536 blocks, balanced XCD mapping (r11), length early-exit (r10).
// ABF16 (fast path): A+B bf16 via global_load_lds. Counted-vmcnt pipeline:
//   A (activations, L3/HBM-latency) 3-deep ring -> staged 2 iters ahead;
//   B (weights, L2/L3-warm) 2-deep -> 1 iter ahead. Per iter: issue B(t+1),
//   then A(t+2); compute; `s_waitcnt vmcnt(4)` (A(t+2) stays in flight,
//   never 0 mid-loop); raw s_barrier + sched_barrier(0) (rule #18).
// !ABF16 fallback: r12's f32 reg-stage + syncthreads 2-phase (unchanged).
template <bool ABF16>
__global__ __launch_bounds__(256) void gemm_fused(
    const float* __restrict__ frF, const float* __restrict__ enF,
    const uint16_t* __restrict__ frB, const uint16_t* __restrict__ enB,
    const uint16_t* __restrict__ wq, const uint16_t* __restrict__ wkv,
    const float* __restrict__ bq, const float* __restrict__ bkv,
    const int* __restrict__ l_en_p, const int* __restrict__ l_fr_p,
    uint16_t* __restrict__ Qb,       // [B,H,S,DH] bf16, pre-scaled
    uint16_t* __restrict__ Kb,       // [B,H,S,DH] bf16
    uint16_t* __restrict__ Vb) {     // [B,H,DH,S] bf16
  __shared__ __attribute__((aligned(16))) uint16_t As[ABF16 ? 3 : 2][128 * 64];
  __shared__ __attribute__((aligned(16))) uint16_t Bs[2][128 * 64];
  const int t = threadIdx.x;
  const int lane = t & 63;
  const int w = t >> 6;
  const int wm = w >> 1, wn = w & 1;
  const int l15 = lane & 15, lg = lane >> 4;

  const int orig = blockIdx.x;                 // 1536 = 8 xcd * 192 slots
  const int xcd = orig & 7;
  const int slot = orig >> 3;                  // 0..191
  const bool isQ = slot < 64;
  int b, bn;
  if (isQ) { b = slot >> 3; bn = (slot & 7) * 128; }
  else { int s2 = slot - 64; b = s2 >> 4; bn = (s2 & 15) * 128; }
  const int i = (xcd - b) & 7;                 // m-tile index within batch
  const int bm = b * 1024 + i * 128;

  const int need = isQ ? read_len(l_fr_p, b) : read_len(l_en_p, b);
  if (i * 128 >= need) return;

  const uint16_t* Bw = isQ ? wq : wkv;
  const float* bias = isQ ? bq : bkv;
  const float scale = isQ ? 0.03125f : 1.0f;
  const uint16_t* Ab = isQ ? frB : enB;
  const float* Af = isQ ? frF : enF;

  f32x4 acc[4][4];
#pragma unroll
  for (int ii = 0; ii < 4; ++ii)
#pragma unroll
    for (int j = 0; j < 4; ++j) acc[ii][j] = (f32x4){0.f, 0.f, 0.f, 0.f};

  auto stageB = [&](int buf, int kt) {
#pragma unroll
    for (int ii = 0; ii < 4; ++ii) {
      int g = t + 256 * ii;           // LDS slot granule (16B units)
      int L = g ^ ((g >> 3) & 7);     // logical granule it must hold
      int row = L >> 3, k8 = L & 7;
      GLDS16(Bw + (size_t)(bn + row) * 1024 + kt + k8 * 8, &Bs[buf][g * 8]);
    }
  };
  auto stageA_bf = [&](int buf, int kt) {
#pragma unroll
    for (int ii = 0; ii < 4; ++ii) {
      int g = t + 256 * ii;
      int L = g ^ ((g >> 3) & 7);
      int row = L >> 3, k8 = L & 7;
      GLDS16(Ab + (size_t)(bm + row) * 1024 + kt + k8 * 8, &As[buf][g * 8]);
    }
  };
  auto computeAB = [&](int bufA, int bufB) {
#pragma unroll
    for (int ks = 0; ks < 2; ++ks) {
      const int kb = ks * 64 + lg * 16;  // byte offset within a 128B row
      bf16x8 af[4], bf[4];
#pragma unroll
      for (int mf = 0; mf < 4; ++mf) {
        int row = wm * 64 + mf * 16 + l15;
        int byte = (row * 128 + kb) ^ ((row & 7) << 4);
        af[mf] = *reinterpret_cast<const bf16x8*>(
            reinterpret_cast<const char*>(As[bufA]) + byte);
      }
#pragma unroll
      for (int nf = 0; nf < 4; ++nf) {
        int row = wn * 64 + nf * 16 + l15;
        int byte = (row * 128 + kb) ^ ((row & 7) << 4);
        bf[nf] = *reinterpret_cast<const bf16x8*>(
            reinterpret_cast<const char*>(Bs[bufB]) + byte);
      }
#pragma unroll
      for (int mf = 0; mf < 4; ++mf)
#pragma unroll
        for (int nf = 0; nf < 4; ++nf)
          acc[mf][nf] = __builtin_amdgcn_mfma_f32_16x16x32_bf16(
              af[mf], bf[nf], acc[mf][nf], 0, 0, 0);
    }
  };

  if (ABF16) {
    // ---- counted-vmcnt pipeline: A 3-deep (2-ahead), B 2-deep (1-ahead) ----
    stageA_bf(0, 0);   // 4 loads
    stageB(0, 0);      // 4 loads
    stageA_bf(1, 64);  // 4 loads (stays in flight across the wait)
    asm volatile("s_waitcnt vmcnt(4)" ::: "memory");  // A0,B0 done; A1 flying
    __builtin_amdgcn_s_barrier();
    __builtin_amdgcn_sched_barrier(0);
    int aC = 0, bC = 0;
    for (int tt = 0; tt < 16; ++tt) {
      if (tt + 1 < 16) stageB(bC ^ 1, (tt + 1) * 64);               // 4 loads
      if (tt + 2 < 16) stageA_bf(aC >= 1 ? aC - 1 : aC + 2, (tt + 2) * 64);
      computeAB(aC, bC);
      if (tt < 15) {
        // Need A(t+1),B(t+1) complete; leave A(t+2)'s 4 loads in flight.
        if (tt < 14) asm volatile("s_waitcnt vmcnt(4)" ::: "memory");
        else         asm volatile("s_waitcnt vmcnt(0)" ::: "memory");
        __builtin_amdgcn_s_barrier();
        __builtin_amdgcn_sched_barrier(0);
      }
      aC = (aC == 2) ? 0 : aC + 1;
      bC ^= 1;
    }
  } else {
    // ---- fallback: f32 A reg-staged, __syncthreads 2-phase (r12) ----
    float4 ar0[4], ar1[4];
    auto loadA_f32 = [&](int kt) {
#pragma unroll
      for (int ii = 0; ii < 4; ++ii) {
        int L = t + 256 * ii;
        int row = L >> 3, k8 = L & 7;
        const float* src = Af + (size_t)(bm + row) * 1024 + kt + k8 * 8;
        ar0[ii] = *reinterpret_cast<const float4*>(src);
        ar1[ii] = *reinterpret_cast<const float4*>(src + 4);
      }
    };
    auto writeA = [&](int buf) {
#pragma unroll
      for (int ii = 0; ii < 4; ++ii) {
        int L = t + 256 * ii;
        int row = L >> 3, k8 = L & 7;
        ushortx8 o;
        o[0] = f2bf(ar0[ii].x); o[1] = f2bf(ar0[ii].y);
        o[2] = f2bf(ar0[ii].z); o[3] = f2bf(ar0[ii].w);
        o[4] = f2bf(ar1[ii].x); o[5] = f2bf(ar1[ii].y);
        o[6] = f2bf(ar1[ii].z); o[7] = f2bf(ar1[ii].w);
        int byte = (row * 128 + k8 * 16) ^ ((row & 7) << 4);
        *reinterpret_cast<ushortx8*>(reinterpret_cast<char*>(As[buf]) + byte) = o;
      }
    };
    loadA_f32(0);
    stageB(0, 0);
    writeA(0);
    __syncthreads();
#pragma unroll 2
    for (int tt = 0; tt < 16; ++tt) {
      const int cur = tt & 1;
      const int ktn = (tt + 1) * 64;
      if (tt < 15) { stageB(cur ^ 1, ktn); loadA_f32(ktn); }
      computeAB(cur, cur);
      if (tt < 15) writeA(cur ^ 1);
      __syncthreads();
    }
  }

  // Epilogue: add bias, scale, scatter bf16 to attention layouts.
#pragma unroll
  for (int mf = 0; mf < 4; ++mf) {
#pragma unroll
    for (int nf = 0; nf < 4; ++nf) {
      int n = bn + wn * 64 + nf * 16 + l15;
      float bv = bias[n];
#pragma unroll
      for (int r = 0; r < 4; ++r) {
        int m = bm + wm * 64 + mf * 16 + lg * 4 + r;
        float v = (acc[mf][nf][r] + bv) * scale;
        uint16_t o = f2bf(v);
        int bb = m >> 10, s = m & 1023;
        if (isQ) {
          int h = n >> 6, d = n & 63;
          Qb[((((bb * 16 + h) << 10) | s) << 6) | d] = o;
        } else if (n < 1024) {
          int h = n >> 6, d = n & 63;
          Kb[((((bb * 16 + h) << 10) | s) << 6) | d] = o;
        } else {
          int n2 = n - 1024;
          int h = n2 >> 6, d = n2 & 63;
          Vb[((((bb * 16 + h) << 6) | d) << 10) | s] = o;
        }
      }
    }
  }
}

// ---------------- Flash attention (unchanged from r15) ----------------
// 1024 blocks x 512 threads (8 waves), QBLK=128, K/V 2-phase dbuf,
// defer-max (THR=8), T5 setprio, balanced XCD mapping (XCD = h&7).
__global__ __launch_bounds__(512) void attn_kernel(
    const uint16_t* __restrict__ Qb,  // [B,H,S,DH] bf16, pre-scaled
    const uint16_t* __restrict__ Kb,  // [B,H,S,DH] bf16
    const uint16_t* __restrict__ Vt,  // [B,H,DH,S] bf16
    const int* __restrict__ l_en_p, const int* __restrict__ l_fr_p,
    float* __restrict__ out) {        // [B,S,D] f32
  __shared__ __attribute__((aligned(16))) uint16_t Ks[2][64 * 64];
  __shared__ __attribute__((aligned(16))) uint16_t Vs[2][64 * 64];
  __shared__ __attribute__((aligned(16))) bf16_t Ps[8][16][72];
  const int t = threadIdx.x;
  const int lane = t & 63, w = t >> 6;          // w in 0..7
  const int l15 = lane & 15, lg = lane >> 4;
  const int orig = blockIdx.x;
  const int xcd = orig & 7;
  const int slot = orig >> 3;                  // 0..127
  const int b = slot >> 4;
  const int rest = slot & 15;
  const int h = xcd + 8 * (rest >> 3);
  const int q0 = (rest & 7) << 7;              // 128-row tile
  const int bh = b * 16 + h;
  const int len_en = read_len(l_en_p, b);
  const int len_fr = read_len(l_fr_p, b);

  if (q0 >= len_fr) {
    for (int i = t; i < 128 * 64; i += 512) {
      int rr = i >> 6, cc = i & 63;
      out[(size_t)(b * 1024 + q0 + rr) * 1024 + h * 64 + cc] = 0.f;
    }
    return;
  }

  const uint16_t* qbase =
      Qb + ((size_t)bh * 1024 + q0 + w * 16 + l15) * 64 + lg * 8;
  const bf16x8 aq0 = *reinterpret_cast<const bf16x8*>(qbase);
  const bf16x8 aq1 = *reinterpret_cast<const bf16x8*>(qbase + 32);

  float mrow[4], lrow[4];
  f32x4 oacc[4];
#pragma unroll
  for (int r = 0; r < 4; ++r) { mrow[r] = -1e30f; lrow[r] = 0.f; }
#pragma unroll
  for (int df = 0; df < 4; ++df) oacc[df] = (f32x4){0.f, 0.f, 0.f, 0.f};

  auto stage = [&](int buf, int j0) {
    int g = t;
    int L = g ^ ((g >> 3) & 7);
    int row = L >> 3, k8 = L & 7;
    GLDS16(Kb + ((size_t)bh * 1024 + j0 + row) * 64 + k8 * 8, &Ks[buf][g * 8]);
    GLDS16(Vt + ((size_t)bh * 64 + row) * 1024 + j0 + k8 * 8, &Vs[buf][g * 8]);
  };

  const int ntiles = (len_en + 63) >> 6;
  stage(0, 0);
  __syncthreads();

  for (int tt = 0; tt < ntiles; ++tt) {
    const int cur = tt & 1;
    const int j0 = tt * 64;
    if (tt + 1 < ntiles) stage(cur ^ 1, (tt + 1) * 64);

    f32x4 sc[4];
#pragma unroll
    for (int nf = 0; nf < 4; ++nf) sc[nf] = (f32x4){0.f, 0.f, 0.f, 0.f};
    __builtin_amdgcn_s_setprio(1);
#pragma unroll
    for (int ks = 0; ks < 2; ++ks) {
      const bf16x8 aq = ks ? aq1 : aq0;
      const int kb = ks * 64 + lg * 16;
#pragma unroll
      for (int nf = 0; nf < 4; ++nf) {
        int row = nf * 16 + l15;
        int byte = (row * 128 + kb) ^ ((row & 7) << 4);
        bf16x8 bk = *reinterpret_cast<const bf16x8*>(
            reinterpret_cast<const char*>(Ks[cur]) + byte);
        sc[nf] = __builtin_amdgcn_mfma_f32_16x16x32_bf16(aq, bk, sc[nf], 0, 0, 0);
      }
    }
    __builtin_amdgcn_s_setprio(0);
#pragma unroll
    for (int nf = 0; nf < 4; ++nf) {
      int col = j0 + nf * 16 + l15;
      if (col >= len_en) sc[nf] = (f32x4){-1e30f, -1e30f, -1e30f, -1e30f};
    }
    float tm[4];
#pragma unroll
    for (int r = 0; r < 4; ++r)
      tm[r] = fmaxf(fmaxf(sc[0][r], sc[1][r]), fmaxf(sc[2][r], sc[3][r]));
#pragma unroll
    for (int off = 1; off < 16; off <<= 1)
#pragma unroll
      for (int r = 0; r < 4; ++r) tm[r] = fmaxf(tm[r], __shfl_xor(tm[r], off));

    bool small = (tm[0] <= mrow[0] + 8.f) && (tm[1] <= mrow[1] + 8.f) &&
                 (tm[2] <= mrow[2] + 8.f) && (tm[3] <= mrow[3] + 8.f);
    if (!__all(small)) {
      float fac[4];
#pragma unroll
      for (int r = 0; r < 4; ++r) {
        float mn = fmaxf(mrow[r], tm[r]);
        fac[r] = __expf(mrow[r] - mn);
        mrow[r] = mn;
      }
#pragma unroll
      for (int r = 0; r < 4; ++r) lrow[r] *= fac[r];
#pragma unroll
      for (int df = 0; df < 4; ++df)
#pragma unroll
        for (int r = 0; r < 4; ++r) oacc[df][r] *= fac[r];
    }
    float ps[4] = {0.f, 0.f, 0.f, 0.f};
#pragma unroll
    for (int nf = 0; nf < 4; ++nf)
#pragma unroll
      for (int r = 0; r < 4; ++r) {
        float p = __expf(sc[nf][r] - mrow[r]);
        ps[r] += p;
        Ps[w][lg * 4 + r][nf * 16 + l15] = (bf16_t)p;
      }
#pragma unroll
    for (int off = 1; off < 16; off <<= 1)
#pragma unroll
      for (int r = 0; r < 4; ++r) ps[r] += __shfl_xor(ps[r], off);
#pragma unroll
    for (int r = 0; r < 4; ++r) lrow[r] += ps[r];

    __builtin_amdgcn_s_setprio(1);
#pragma unroll
    for (int ks = 0; ks < 2; ++ks) {
      const bf16x8 pa = *reinterpret_cast<const bf16x8*>(
          &Ps[w][l15][0] + ks * 32 + lg * 8);
#pragma unroll
      for (int df = 0; df < 4; ++df) {
        int row = df * 16 + l15;
        int byte = (row * 128 + ks * 64 + lg * 16) ^ ((row & 7) << 4);
        bf16x8 bv = *reinterpret_cast<const bf16x8*>(
            reinterpret_cast<const char*>(Vs[cur]) + byte);
        oacc[df] = __builtin_amdgcn_mfma_f32_16x16x32_bf16(pa, bv, oacc[df], 0, 0, 0);
      }
    }
    __builtin_amdgcn_s_setprio(0);
    __syncthreads();
  }

#pragma unroll
  for (int df = 0; df < 4; ++df)
#pragma unroll
    for (int r = 0; r < 4; ++r) {
      int q = q0 + w * 16 + lg * 4 + r;
      float inv = (q < len_fr && lrow[r] > 0.f) ? 1.0f / lrow[r] : 0.f;
      out[(size_t)(b * 1024 + q) * 1024 + h * 64 + df * 16 + l15] =
          oacc[df][r] * inv;
    }
}

// ---------------- launch ----------------
extern "C" void kernel_launch(void* const* d_in, const int* in_sizes, int n_in,
                              void* d_out, int out_size, void* d_ws,
                              size_t ws_size, hipStream_t stream) {
  const float* en = (const float*)d_in[0];
  const float* fr = (const float*)d_in[1];
  const int* l_en = (const int*)d_in[2];
  const int* l_fr = (const int*)d_in[3];
  const float* wq = (const float*)d_in[4];
  const float* bq = (const float*)d_in[5];
  const float* wkv = (const float*)d_in[6];
  const float* bkv = (const float*)d_in[7];
  float* out = (float*)d_out;  // output dtype is FLOAT32

  // Workspace layout (bytes):
  // wq_bf 0..2M | wkv_bf 2M..6M | Qbuf 6M..23M | Kbuf 23M..40M | Vtbuf 40M..56.6M
  // [fast path] fr_bf 56.6M..73.4M | en_bf 73.4M..90.2M
  char* ws = (char*)d_ws;
  uint16_t* wq_bf = (uint16_t*)(ws);
  uint16_t* wkv_bf = (uint16_t*)(ws + 2097152);
  uint16_t* Qbuf = (uint16_t*)(ws + 6291456);
  uint16_t* Kbuf = (uint16_t*)(ws + 23068672);
  uint16_t* Vtbuf = (uint16_t*)(ws + 39845888);
  uint16_t* fr_bf = (uint16_t*)(ws + 56623104);
  uint16_t* en_bf = (uint16_t*)(ws + 73400320);
  const bool pre = ws_size >= 90177536ull;

  if (pre) {
    cvt4_kernel<<<19456, 256, 0, stream>>>(wq, wq_bf, 1048576,
                                           wkv, wkv_bf, 2097152,
                                           fr, fr_bf, 8388608,
                                           en, en_bf, 8388608,
                                           l_fr, l_en);
    gemm_fused<true><<<1536, 256, 0, stream>>>(nullptr, nullptr, fr_bf, en_bf,
                                               wq_bf, wkv_bf, bq, bkv,
                                               l_en, l_fr, Qbuf, Kbuf, Vtbuf);
  } else {
    cvt4_kernel<<<3072, 256, 0, stream>>>(wq, wq_bf, 1048576,
                                          wkv, wkv_bf, 2097152,
                                          nullptr, nullptr, 0,
                                          nullptr, nullptr, 0,
                                          nullptr, nullptr);
    gemm_fused<false><<<1536, 256, 0, stream>>>(fr, en, nullptr, nullptr,
                                                wq_bf, wkv_bf, bq, bkv,
                                                l_en, l_fr, Qbuf, Kbuf, Vtbuf);
  }

  attn_kernel<<<1024, 512, 0, stream>>>(Qbuf, Kbuf, Vtbuf, l_en, l_fr, out);
}

// Round 17
// 113.929 us; speedup vs baseline: 1.2909x; 1.0137x over previous
//
#include <hip/hip_runtime.h>
#include <hip/hip_bf16.h>
#include <stdint.h>

// Problem constants: B=8, S=1024, D=1024, H=16, DH=64
typedef __bf16 bf16_t;
typedef bf16_t bf16x8 __attribute__((ext_vector_type(8)));
typedef float f32x4 __attribute__((ext_vector_type(4)));
typedef unsigned short ushortx8 __attribute__((ext_vector_type(8)));

__device__ __forceinline__ uint16_t f2bf(float f) {
  uint32_t u = __float_as_uint(f);
  uint32_t r = u + 0x7FFFu + ((u >> 16) & 1u);  // RNE
  return (uint16_t)(r >> 16);
}

__device__ __forceinline__ int read_len(const int* __restrict__ p, int b) {
  bool is64 = (p[1] == 0) | (p[3] == 0) | (p[5] == 0) | (p[7] == 0);
  return is64 ? p[2 * b] : p[b];
}

#define GLDS16(gp, lp)                                                   \
  __builtin_amdgcn_global_load_lds(                                      \
      (const __attribute__((address_space(1))) uint32_t*)(gp),           \
      (__attribute__((address_space(3))) uint32_t*)(lp), 16, 0, 0)

// ------ merged f32 -> bf16 convert over up to 4 segments (granule = 4) ------
__global__ void cvt4_kernel(const float* __restrict__ s0, uint16_t* __restrict__ d0, int n0,
                            const float* __restrict__ s1, uint16_t* __restrict__ d1, int n1,
                            const float* __restrict__ s2, uint16_t* __restrict__ d2, int n2,
                            const float* __restrict__ s3, uint16_t* __restrict__ d3, int n3,
                            const int* __restrict__ msk2, const int* __restrict__ msk3) {
  int e = (blockIdx.x * blockDim.x + threadIdx.x) * 4;
  const float* s;
  uint16_t* d;
  const int* msk = nullptr;
  if (e < n0) { s = s0 + e; d = d0 + e; }
  else if ((e -= n0) < n1) { s = s1 + e; d = d1 + e; }
  else if ((e -= n1) < n2) { s = s2 + e; d = d2 + e; msk = msk2; }
  else if ((e -= n2) < n3) { s = s3 + e; d = d3 + e; msk = msk3; }
  else return;
  if (msk) {
    int row = (e >> 10) & 1023, b = e >> 20;   // 1024 elems/row, 1M elems/batch
    int need = (read_len(msk, b) + 127) & ~127;
    if (row >= need) return;
  }
  const float4 v = *reinterpret_cast<const float4*>(s);
  ushort4 o;
  o.x = f2bf(v.x); o.y = f2bf(v.y); o.z = f2bf(v.z); o.w = f2bf(v.w);
  *reinterpret_cast<ushort4*>(d) = o;
}

// -------- Fast fused NT GEMM (512 threads = 8 waves, bf16 A+B via GLDS) ----
// 1536 blocks, balanced XCD mapping (r11), length early-exit (r10).
// Wave grid 2x4: wave w owns a 64x32 sub-tile (acc 4x2). 16 waves/CU.
// Counted-vmcnt pipeline: A 3-deep ring (2-ahead), B 2-deep (1-ahead);
// `s_waitcnt vmcnt(2)` steady-state (never 0 mid-loop); raw s_barrier +
// sched_barrier(0) after each wait (rule #18).
__global__ __launch_bounds__(512) void gemm_fast(
    const uint16_t* __restrict__ frB, const uint16_t* __restrict__ enB,
    const uint16_t* __restrict__ wq, const uint16_t* __restrict__ wkv,
    const float* __restrict__ bq, const float* __restrict__ bkv,
    const int* __restrict__ l_en_p, const int* __restrict__ l_fr_p,
    uint16_t* __restrict__ Qb,       // [B,H,S,DH] bf16, pre-scaled
    uint16_t* __restrict__ Kb,       // [B,H,S,DH] bf16
    uint16_t* __restrict__ Vb) {     // [B,H,DH,S] bf16
  __shared__ __attribute__((aligned(16))) uint16_t As[3][128 * 64];
  __shared__ __attribute__((aligned(16))) uint16_t Bs[2][128 * 64];
  const int t = threadIdx.x;
  const int lane = t & 63;
  const int w = t >> 6;                        // 0..7
  const int wm = w >> 2, wn = w & 3;           // 2 x 4 wave grid
  const int l15 = lane & 15, lg = lane >> 4;

  const int orig = blockIdx.x;                 // 1536 = 8 xcd * 192 slots
  const int xcd = orig & 7;
  const int slot = orig >> 3;                  // 0..191
  const bool isQ = slot < 64;
  int b, bn;
  if (isQ) { b = slot >> 3; bn = (slot & 7) * 128; }
  else { int s2 = slot - 64; b = s2 >> 4; bn = (s2 & 15) * 128; }
  const int i = (xcd - b) & 7;                 // m-tile index within batch
  const int bm = b * 1024 + i * 128;

  const int need = isQ ? read_len(l_fr_p, b) : read_len(l_en_p, b);
  if (i * 128 >= need) return;

  const uint16_t* Bw = isQ ? wq : wkv;
  const float* bias = isQ ? bq : bkv;
  const float scale = isQ ? 0.03125f : 1.0f;
  const uint16_t* Ab = isQ ? frB : enB;

  f32x4 acc[4][2];
#pragma unroll
  for (int ii = 0; ii < 4; ++ii)
#pragma unroll
    for (int j = 0; j < 2; ++j) acc[ii][j] = (f32x4){0.f, 0.f, 0.f, 0.f};

  // Tile = 1024 granules (16B); 512 threads x 2. Swizzled source, linear dest.
  auto stageB = [&](int buf, int kt) {
#pragma unroll
    for (int ii = 0; ii < 2; ++ii) {
      int g = t + 512 * ii;
      int L = g ^ ((g >> 3) & 7);
      int row = L >> 3, k8 = L & 7;
      GLDS16(Bw + (size_t)(bn + row) * 1024 + kt + k8 * 8, &Bs[buf][g * 8]);
    }
  };
  auto stageA = [&](int buf, int kt) {
#pragma unroll
    for (int ii = 0; ii < 2; ++ii) {
      int g = t + 512 * ii;
      int L = g ^ ((g >> 3) & 7);
      int row = L >> 3, k8 = L & 7;
      GLDS16(Ab + (size_t)(bm + row) * 1024 + kt + k8 * 8, &As[buf][g * 8]);
    }
  };
  auto computeAB = [&](int bufA, int bufB) {
#pragma unroll
    for (int ks = 0; ks < 2; ++ks) {
      const int kb = ks * 64 + lg * 16;  // byte offset within a 128B row
      bf16x8 af[4], bf[2];
#pragma unroll
      for (int mf = 0; mf < 4; ++mf) {
        int row = wm * 64 + mf * 16 + l15;
        int byte = (row * 128 + kb) ^ ((row & 7) << 4);
        af[mf] = *reinterpret_cast<const bf16x8*>(
            reinterpret_cast<const char*>(As[bufA]) + byte);
      }
#pragma unroll
      for (int nf = 0; nf < 2; ++nf) {
        int row = wn * 32 + nf * 16 + l15;
        int byte = (row * 128 + kb) ^ ((row & 7) << 4);
        bf[nf] = *reinterpret_cast<const bf16x8*>(
            reinterpret_cast<const char*>(Bs[bufB]) + byte);
      }
#pragma unroll
      for (int mf = 0; mf < 4; ++mf)
#pragma unroll
        for (int nf = 0; nf < 2; ++nf)
          acc[mf][nf] = __builtin_amdgcn_mfma_f32_16x16x32_bf16(
              af[mf], bf[nf], acc[mf][nf], 0, 0, 0);
    }
  };

  // ---- counted-vmcnt pipeline: A 3-deep (2-ahead), B 2-deep (1-ahead) ----
  stageA(0, 0);      // 2 loads
  stageB(0, 0);      // 2 loads
  stageA(1, 64);     // 2 loads (stay in flight across the wait)
  asm volatile("s_waitcnt vmcnt(2)" ::: "memory");  // A0,B0 done; A1 flying
  __builtin_amdgcn_s_barrier();
  __builtin_amdgcn_sched_barrier(0);
  int aC = 0, bC = 0;
  for (int tt = 0; tt < 16; ++tt) {
    if (tt + 1 < 16) stageB(bC ^ 1, (tt + 1) * 64);               // 2 loads
    if (tt + 2 < 16) stageA(aC >= 1 ? aC - 1 : aC + 2, (tt + 2) * 64);  // 2
    computeAB(aC, bC);
    if (tt < 15) {
      // Need A(t+1),B(t+1) complete; leave A(t+2)'s 2 loads in flight.
      if (tt < 14) asm volatile("s_waitcnt vmcnt(2)" ::: "memory");
      else         asm volatile("s_waitcnt vmcnt(0)" ::: "memory");
      __builtin_amdgcn_s_barrier();
      __builtin_amdgcn_sched_barrier(0);
    }
    aC = (aC == 2) ? 0 : aC + 1;
    bC ^= 1;
  }

  // Epilogue: add bias, scale, scatter bf16 to attention layouts.
#pragma unroll
  for (int mf = 0; mf < 4; ++mf) {
#pragma unroll
    for (int nf = 0; nf < 2; ++nf) {
      int n = bn + wn * 32 + nf * 16 + l15;
      float bv = bias[n];
#pragma unroll
      for (int r = 0; r < 4; ++r) {
        int m = bm + wm * 64 + mf * 16 + lg * 4 + r;
        float v = (acc[mf][nf][r] + bv) * scale;
        uint16_t o = f2bf(v);
        int bb = m >> 10, s = m & 1023;
        if (isQ) {
          int h = n >> 6, d = n & 63;
          Qb[((((bb * 16 + h) << 10) | s) << 6) | d] = o;
        } else if (n < 1024) {
          int h = n >> 6, d = n & 63;
          Kb[((((bb * 16 + h) << 10) | s) << 6) | d] = o;
        } else {
          int n2 = n - 1024;
          int h = n2 >> 6, d = n2 & 63;
          Vb[((((bb * 16 + h) << 6) | d) << 10) | s] = o;
        }
      }
    }
  }
}

// -------- Fallback fused GEMM (256 threads, f32 A reg-staged; r12 path) ----
__global__ __launch_bounds__(256) void gemm_fb(
    const float* __restrict__ frF, const float* __restrict__ enF,
    const uint16_t* __restrict__ wq, const uint16_t* __restrict__ wkv,
    const float* __restrict__ bq, const float* __restrict__ bkv,
    const int* __restrict__ l_en_p, const int* __restrict__ l_fr_p,
    uint16_t* __restrict__ Qb, uint16_t* __restrict__ Kb,
    uint16_t* __restrict__ Vb) {
  __shared__ __attribute__((aligned(16))) uint16_t As[2][128 * 64];
  __shared__ __attribute__((aligned(16))) uint16_t Bs[2][128 * 64];
  const int t = threadIdx.x;
  const int lane = t & 63;
  const int w = t >> 6;
  const int wm = w >> 1, wn = w & 1;
  const int l15 = lane & 15, lg = lane >> 4;

  const int orig = blockIdx.x;
  const int xcd = orig & 7;
  const int slot = orig >> 3;
  const bool isQ = slot < 64;
  int b, bn;
  if (isQ) { b = slot >> 3; bn = (slot & 7) * 128; }
  else { int s2 = slot - 64; b = s2 >> 4; bn = (s2 & 15) * 128; }
  const int i = (xcd - b) & 7;
  const int bm = b * 1024 + i * 128;

  const int need = isQ ? read_len(l_fr_p, b) : read_len(l_en_p, b);
  if (i * 128 >= need) return;

  const uint16_t* Bw = isQ ? wq : wkv;
  const float* bias = isQ ? bq : bkv;
  const float scale = isQ ? 0.03125f : 1.0f;
  const float* Af = isQ ? frF : enF;

  f32x4 acc[4][4];
#pragma unroll
  for (int ii = 0; ii < 4; ++ii)
#pragma unroll
    for (int j = 0; j < 4; ++j) acc[ii][j] = (f32x4){0.f, 0.f, 0.f, 0.f};

  float4 ar0[4], ar1[4];

  auto stageB = [&](int buf, int kt) {
#pragma unroll
    for (int ii = 0; ii < 4; ++ii) {
      int g = t + 256 * ii;
      int L = g ^ ((g >> 3) & 7);
      int row = L >> 3, k8 = L & 7;
      GLDS16(Bw + (size_t)(bn + row) * 1024 + kt + k8 * 8, &Bs[buf][g * 8]);
    }
  };
  auto loadA_f32 = [&](int kt) {
#pragma unroll
    for (int ii = 0; ii < 4; ++ii) {
      int L = t + 256 * ii;
      int row = L >> 3, k8 = L & 7;
      const float* src = Af + (size_t)(bm + row) * 1024 + kt + k8 * 8;
      ar0[ii] = *reinterpret_cast<const float4*>(src);
      ar1[ii] = *reinterpret_cast<const float4*>(src + 4);
    }
  };
  auto writeA = [&](int buf) {
#pragma unroll
    for (int ii = 0; ii < 4; ++ii) {
      int L = t + 256 * ii;
      int row = L >> 3, k8 = L & 7;
      ushortx8 o;
      o[0] = f2bf(ar0[ii].x); o[1] = f2bf(ar0[ii].y);
      o[2] = f2bf(ar0[ii].z); o[3] = f2bf(ar0[ii].w);
      o[4] = f2bf(ar1[ii].x); o[5] = f2bf(ar1[ii].y);
      o[6] = f2bf(ar1[ii].z); o[7] = f2bf(ar1[ii].w);
      int byte = (row * 128 + k8 * 16) ^ ((row & 7) << 4);
      *reinterpret_cast<ushortx8*>(reinterpret_cast<char*>(As[buf]) + byte) = o;
    }
  };
  auto compute = [&](int buf) {
#pragma unroll
    for (int ks = 0; ks < 2; ++ks) {
      const int kb = ks * 64 + lg * 16;
      bf16x8 af[4], bf[4];
#pragma unroll
      for (int mf = 0; mf < 4; ++mf) {
        int row = wm * 64 + mf * 16 + l15;
        int byte = (row * 128 + kb) ^ ((row & 7) << 4);
        af[mf] = *reinterpret_cast<const bf16x8*>(
            reinterpret_cast<const char*>(As[buf]) + byte);
      }
#pragma unroll
      for (int nf = 0; nf < 4; ++nf) {
        int row = wn * 64 + nf * 16 + l15;
        int byte = (row * 128 + kb) ^ ((row & 7) << 4);
        bf[nf] = *reinterpret_cast<const bf16x8*>(
            reinterpret_cast<const char*>(Bs[buf]) + byte);
      }
#pragma unroll
      for (int mf = 0; mf < 4; ++mf)
#pragma unroll
        for (int nf = 0; nf < 4; ++nf)
          acc[mf][nf] = __builtin_amdgcn_mfma_f32_16x16x32_bf16(
              af[mf], bf[nf], acc[mf][nf], 0, 0, 0);
    }
  };
  loadA_f32(0);
  stageB(0, 0);
  writeA(0);
  __syncthreads();
#pragma unroll 2
  for (int tt = 0; tt < 16; ++tt) {
    const int cur = tt & 1;
    const int ktn = (tt + 1) * 64;
    if (tt < 15) { stageB(cur ^ 1, ktn); loadA_f32(ktn); }
    compute(cur);
    if (tt < 15) writeA(cur ^ 1);
    __syncthreads();
  }

#pragma unroll
  for (int mf = 0; mf < 4; ++mf) {
#pragma unroll
    for (int nf = 0; nf < 4; ++nf) {
      int n = bn + wn * 64 + nf * 16 + l15;
      float bv = bias[n];
#pragma unroll
      for (int r = 0; r < 4; ++r) {
        int m = bm + wm * 64 + mf * 16 + lg * 4 + r;
        float v = (acc[mf][nf][r] + bv) * scale;
        uint16_t o = f2bf(v);
        int bb = m >> 10, s = m & 1023;
        if (isQ) {
          int h = n >> 6, d = n & 63;
          Qb[((((bb * 16 + h) << 10) | s) << 6) | d] = o;
        } else if (n < 1024) {
          int h = n >> 6, d = n & 63;
          Kb[((((bb * 16 + h) << 10) | s) << 6) | d] = o;
        } else {
          int n2 = n - 1024;
          int h = n2 >> 6, d = n2 & 63;
          Vb[((((bb * 16 + h) << 6) | d) << 10) | s] = o;
        }
      }
    }
  }
}

// ---------------- Flash attention (unchanged from r15) ----------------
// 1024 blocks x 512 threads (8 waves), QBLK=128, K/V 2-phase dbuf,
// defer-max (THR=8), T5 setprio, balanced XCD mapping (XCD = h&7).
__global__ __launch_bounds__(512) void attn_kernel(
    const uint16_t* __restrict__ Qb,  // [B,H,S,DH] bf16, pre-scaled
    const uint16_t* __restrict__ Kb,  // [B,H,S,DH] bf16
    const uint16_t* __restrict__ Vt,  // [B,H,DH,S] bf16
    const int* __restrict__ l_en_p, const int* __restrict__ l_fr_p,
    float* __restrict__ out) {        // [B,S,D] f32
  __shared__ __attribute__((aligned(16))) uint16_t Ks[2][64 * 64];
  __shared__ __attribute__((aligned(16))) uint16_t Vs[2][64 * 64];
  __shared__ __attribute__((aligned(16))) bf16_t Ps[8][16][72];
  const int t = threadIdx.x;
  const int lane = t & 63, w = t >> 6;          // w in 0..7
  const int l15 = lane & 15, lg = lane >> 4;
  const int orig = blockIdx.x;
  const int xcd = orig & 7;
  const int slot = orig >> 3;                  // 0..127
  const int b = slot >> 4;
  const int rest = slot & 15;
  const int h = xcd + 8 * (rest >> 3);
  const int q0 = (rest & 7) << 7;              // 128-row tile
  const int bh = b * 16 + h;
  const int len_en = read_len(l_en_p, b);
  const int len_fr = read_len(l_fr_p, b);

  if (q0 >= len_fr) {
    for (int i = t; i < 128 * 64; i += 512) {
      int rr = i >> 6, cc = i & 63;
      out[(size_t)(b * 1024 + q0 + rr) * 1024 + h * 64 + cc] = 0.f;
    }
    return;
  }

  const uint16_t* qbase =
      Qb + ((size_t)bh * 1024 + q0 + w * 16 + l15) * 64 + lg * 8;
  const bf16x8 aq0 = *reinterpret_cast<const bf16x8*>(qbase);
  const bf16x8 aq1 = *reinterpret_cast<const bf16x8*>(qbase + 32);

  float mrow[4], lrow[4];
  f32x4 oacc[4];
#pragma unroll
  for (int r = 0; r < 4; ++r) { mrow[r] = -1e30f; lrow[r] = 0.f; }
#pragma unroll
  for (int df = 0; df < 4; ++df) oacc[df] = (f32x4){0.f, 0.f, 0.f, 0.f};

  auto stage = [&](int buf, int j0) {
    int g = t;
    int L = g ^ ((g >> 3) & 7);
    int row = L >> 3, k8 = L & 7;
    GLDS16(Kb + ((size_t)bh * 1024 + j0 + row) * 64 + k8 * 8, &Ks[buf][g * 8]);
    GLDS16(Vt + ((size_t)bh * 64 + row) * 1024 + j0 + k8 * 8, &Vs[buf][g * 8]);
  };

  const int ntiles = (len_en + 63) >> 6;
  stage(0, 0);
  __syncthreads();

  for (int tt = 0; tt < ntiles; ++tt) {
    const int cur = tt & 1;
    const int j0 = tt * 64;
    if (tt + 1 < ntiles) stage(cur ^ 1, (tt + 1) * 64);

    f32x4 sc[4];
#pragma unroll
    for (int nf = 0; nf < 4; ++nf) sc[nf] = (f32x4){0.f, 0.f, 0.f, 0.f};
    __builtin_amdgcn_s_setprio(1);
#pragma unroll
    for (int ks = 0; ks < 2; ++ks) {
      const bf16x8 aq = ks ? aq1 : aq0;
      const int kb = ks * 64 + lg * 16;
#pragma unroll
      for (int nf = 0; nf < 4; ++nf) {
        int row = nf * 16 + l15;
        int byte = (row * 128 + kb) ^ ((row & 7) << 4);
        bf16x8 bk = *reinterpret_cast<const bf16x8*>(
            reinterpret_cast<const char*>(Ks[cur]) + byte);
        sc[nf] = __builtin_amdgcn_mfma_f32_16x16x32_bf16(aq, bk, sc[nf], 0, 0, 0);
      }
    }
    __builtin_amdgcn_s_setprio(0);
#pragma unroll
    for (int nf = 0; nf < 4; ++nf) {
      int col = j0 + nf * 16 + l15;
      if (col >= len_en) sc[nf] = (f32x4){-1e30f, -1e30f, -1e30f, -1e30f};
    }
    float tm[4];
#pragma unroll
    for (int r = 0; r < 4; ++r)
      tm[r] = fmaxf(fmaxf(sc[0][r], sc[1][r]), fmaxf(sc[2][r], sc[3][r]));
#pragma unroll
    for (int off = 1; off < 16; off <<= 1)
#pragma unroll
      for (int r = 0; r < 4; ++r) tm[r] = fmaxf(tm[r], __shfl_xor(tm[r], off));

    bool small = (tm[0] <= mrow[0] + 8.f) && (tm[1] <= mrow[1] + 8.f) &&
                 (tm[2] <= mrow[2] + 8.f) && (tm[3] <= mrow[3] + 8.f);
    if (!__all(small)) {
      float fac[4];
#pragma unroll
      for (int r = 0; r < 4; ++r) {
        float mn = fmaxf(mrow[r], tm[r]);
        fac[r] = __expf(mrow[r] - mn);
        mrow[r] = mn;
      }
#pragma unroll
      for (int r = 0; r < 4; ++r) lrow[r] *= fac[r];
#pragma unroll
      for (int df = 0; df < 4; ++df)
#pragma unroll
        for (int r = 0; r < 4; ++r) oacc[df][r] *= fac[r];
    }
    float ps[4] = {0.f, 0.f, 0.f, 0.f};
#pragma unroll
    for (int nf = 0; nf < 4; ++nf)
#pragma unroll
      for (int r = 0; r < 4; ++r) {
        float p = __expf(sc[nf][r] - mrow[r]);
        ps[r] += p;
        Ps[w][lg * 4 + r][nf * 16 + l15] = (bf16_t)p;
      }
#pragma unroll
    for (int off = 1; off < 16; off <<= 1)
#pragma unroll
      for (int r = 0; r < 4; ++r) ps[r] += __shfl_xor(ps[r], off);
#pragma unroll
    for (int r = 0; r < 4; ++r) lrow[r] += ps[r];

    __builtin_amdgcn_s_setprio(1);
#pragma unroll
    for (int ks = 0; ks < 2; ++ks) {
      const bf16x8 pa = *reinterpret_cast<const bf16x8*>(
          &Ps[w][l15][0] + ks * 32 + lg * 8);
#pragma unroll
      for (int df = 0; df < 4; ++df) {
        int row = df * 16 + l15;
        int byte = (row * 128 + ks * 64 + lg * 16) ^ ((row & 7) << 4);
        bf16x8 bv = *reinterpret_cast<const bf16x8*>(
            reinterpret_cast<const char*>(Vs[cur]) + byte);
        oacc[df] = __builtin_amdgcn_mfma_f32_16x16x32_bf16(pa, bv, oacc[df], 0, 0, 0);
      }
    }
    __builtin_amdgcn_s_setprio(0);
    __syncthreads();
  }

#pragma unroll
  for (int df = 0; df < 4; ++df)
#pragma unroll
    for (int r = 0; r < 4; ++r) {
      int q = q0 + w * 16 + lg * 4 + r;
      float inv = (q < len_fr && lrow[r] > 0.f) ? 1.0f / lrow[r] : 0.f;
      out[(size_t)(b * 1024 + q) * 1024 + h * 64 + df * 16 + l15] =
          oacc[df][r] * inv;
    }
}

// ---------------- launch ----------------
extern "C" void kernel_launch(void* const* d_in, const int* in_sizes, int n_in,
                              void* d_out, int out_size, void* d_ws,
                              size_t ws_size, hipStream_t stream) {
  const float* en = (const float*)d_in[0];
  const float* fr = (const float*)d_in[1];
  const int* l_en = (const int*)d_in[2];
  const int* l_fr = (const int*)d_in[3];
  const float* wq = (const float*)d_in[4];
  const float* bq = (const float*)d_in[5];
  const float* wkv = (const float*)d_in[6];
  const float* bkv = (const float*)d_in[7];
  float* out = (float*)d_out;  // output dtype is FLOAT32

  // Workspace layout (bytes):
  // wq_bf 0..2M | wkv_bf 2M..6M | Qbuf 6M..23M | Kbuf 23M..40M | Vtbuf 40M..56.6M
  // [fast path] fr_bf 56.6M..73.4M | en_bf 73.4M..90.2M
  char* ws = (char*)d_ws;
  uint16_t* wq_bf = (uint16_t*)(ws);
  uint16_t* wkv_bf = (uint16_t*)(ws + 2097152);
  uint16_t* Qbuf = (uint16_t*)(ws + 6291456);
  uint16_t* Kbuf = (uint16_t*)(ws + 23068672);
  uint16_t* Vtbuf = (uint16_t*)(ws + 39845888);
  uint16_t* fr_bf = (uint16_t*)(ws + 56623104);
  uint16_t* en_bf = (uint16_t*)(ws + 73400320);
  const bool pre = ws_size >= 90177536ull;

  if (pre) {
    cvt4_kernel<<<19456, 256, 0, stream>>>(wq, wq_bf, 1048576,
                                           wkv, wkv_bf, 2097152,
                                           fr, fr_bf, 8388608,
                                           en, en_bf, 8388608,
                                           l_fr, l_en);
    gemm_fast<<<1536, 512, 0, stream>>>(fr_bf, en_bf, wq_bf, wkv_bf, bq, bkv,
                                        l_en, l_fr, Qbuf, Kbuf, Vtbuf);
  } else {
    cvt4_kernel<<<3072, 256, 0, stream>>>(wq, wq_bf, 1048576,
                                          wkv, wkv_bf, 2097152,
                                          nullptr, nullptr, 0,
                                          nullptr, nullptr, 0,
                                          nullptr, nullptr);
    gemm_fb<<<1536, 256, 0, stream>>>(fr, en, wq_bf, wkv_bf, bq, bkv,
                                      l_en, l_fr, Qbuf, Kbuf, Vtbuf);
  }

  attn_kernel<<<1024, 512, 0, stream>>>(Qbuf, Kbuf, Vtbuf, l_en, l_fr, out);
}

// Round 18
// 108.087 us; speedup vs baseline: 1.3606x; 1.0540x over previous
//
#include <hip/hip_runtime.h>
#include <hip/hip_bf16.h>
#include <stdint.h>

// Problem constants: B=8, S=1024, D=1024, H=16, DH=64
typedef __bf16 bf16_t;
typedef bf16_t bf16x8 __attribute__((ext_vector_type(8)));
typedef float f32x4 __attribute__((ext_vector_type(4)));
typedef unsigned short ushortx8 __attribute__((ext_vector_type(8)));

__device__ __forceinline__ uint16_t f2bf(float f) {
  uint32_t u = __float_as_uint(f);
  uint32_t r = u + 0x7FFFu + ((u >> 16) & 1u);  // RNE
  return (uint16_t)(r >> 16);
}

__device__ __forceinline__ int read_len(const int* __restrict__ p, int b) {
  bool is64 = (p[1] == 0) | (p[3] == 0) | (p[5] == 0) | (p[7] == 0);
  return is64 ? p[2 * b] : p[b];
}

#define GLDS16(gp, lp)                                                   \
  __builtin_amdgcn_global_load_lds(                                      \
      (const __attribute__((address_space(1))) uint32_t*)(gp),           \
      (__attribute__((address_space(3))) uint32_t*)(lp), 16, 0, 0)

// ------ merged f32 -> bf16 convert, 8 elems (32B) per thread ------
// Segment order: fr, en (large, masked), then wq, wkv. Masked segments skip
// rows >= ceil128(len) (never read downstream).
__global__ void cvt4_kernel(const float* __restrict__ s0, uint16_t* __restrict__ d0, int n0,
                            const float* __restrict__ s1, uint16_t* __restrict__ d1, int n1,
                            const float* __restrict__ s2, uint16_t* __restrict__ d2, int n2,
                            const float* __restrict__ s3, uint16_t* __restrict__ d3, int n3,
                            const int* __restrict__ msk0, const int* __restrict__ msk1) {
  int e = (blockIdx.x * blockDim.x + threadIdx.x) * 8;
  const float* s;
  uint16_t* d;
  const int* msk = nullptr;
  if (e < n0) { s = s0 + e; d = d0 + e; msk = msk0; }
  else if ((e -= n0) < n1) { s = s1 + e; d = d1 + e; msk = msk1; }
  else if ((e -= n1) < n2) { s = s2 + e; d = d2 + e; }
  else if ((e -= n2) < n3) { s = s3 + e; d = d3 + e; }
  else return;
  if (msk) {
    int row = (e >> 10) & 1023, b = e >> 20;   // 1024 elems/row, 1M elems/batch
    int need = (read_len(msk, b) + 127) & ~127;
    if (row >= need) return;
  }
  const float4 v0 = *reinterpret_cast<const float4*>(s);
  const float4 v1 = *reinterpret_cast<const float4*>(s + 4);
  ushortx8 o;
  o[0] = f2bf(v0.x); o[1] = f2bf(v0.y); o[2] = f2bf(v0.z); o[3] = f2bf(v0.w);
  o[4] = f2bf(v1.x); o[5] = f2bf(v1.y); o[6] = f2bf(v1.z); o[7] = f2bf(v1.w);
  *reinterpret_cast<ushortx8*>(d) = o;
}

// -------- Fast fused NT GEMM (512 threads = 8 waves, bf16 A+B via GLDS) ----
// (unchanged from r17: balanced XCD mapping, length early-exit, A 3-deep /
//  B 2-deep counted-vmcnt pipeline, raw barriers + sched_barrier(0).)
__global__ __launch_bounds__(512) void gemm_fast(
    const uint16_t* __restrict__ frB, const uint16_t* __restrict__ enB,
    const uint16_t* __restrict__ wq, const uint16_t* __restrict__ wkv,
    const float* __restrict__ bq, const float* __restrict__ bkv,
    const int* __restrict__ l_en_p, const int* __restrict__ l_fr_p,
    uint16_t* __restrict__ Qb,       // [B,H,S,DH] bf16, pre-scaled
    uint16_t* __restrict__ Kb,       // [B,H,S,DH] bf16
    uint16_t* __restrict__ Vb) {     // [B,H,DH,S] bf16
  __shared__ __attribute__((aligned(16))) uint16_t As[3][128 * 64];
  __shared__ __attribute__((aligned(16))) uint16_t Bs[2][128 * 64];
  const int t = threadIdx.x;
  const int lane = t & 63;
  const int w = t >> 6;                        // 0..7
  const int wm = w >> 2, wn = w & 3;           // 2 x 4 wave grid
  const int l15 = lane & 15, lg = lane >> 4;

  const int orig = blockIdx.x;                 // 1536 = 8 xcd * 192 slots
  const int xcd = orig & 7;
  const int slot = orig >> 3;                  // 0..191
  const bool isQ = slot < 64;
  int b, bn;
  if (isQ) { b = slot >> 3; bn = (slot & 7) * 128; }
  else { int s2 = slot - 64; b = s2 >> 4; bn = (s2 & 15) * 128; }
  const int i = (xcd - b) & 7;                 // m-tile index within batch
  const int bm = b * 1024 + i * 128;

  const int need = isQ ? read_len(l_fr_p, b) : read_len(l_en_p, b);
  if (i * 128 >= need) return;

  const uint16_t* Bw = isQ ? wq : wkv;
  const float* bias = isQ ? bq : bkv;
  const float scale = isQ ? 0.03125f : 1.0f;
  const uint16_t* Ab = isQ ? frB : enB;

  f32x4 acc[4][2];
#pragma unroll
  for (int ii = 0; ii < 4; ++ii)
#pragma unroll
    for (int j = 0; j < 2; ++j) acc[ii][j] = (f32x4){0.f, 0.f, 0.f, 0.f};

  auto stageB = [&](int buf, int kt) {
#pragma unroll
    for (int ii = 0; ii < 2; ++ii) {
      int g = t + 512 * ii;
      int L = g ^ ((g >> 3) & 7);
      int row = L >> 3, k8 = L & 7;
      GLDS16(Bw + (size_t)(bn + row) * 1024 + kt + k8 * 8, &Bs[buf][g * 8]);
    }
  };
  auto stageA = [&](int buf, int kt) {
#pragma unroll
    for (int ii = 0; ii < 2; ++ii) {
      int g = t + 512 * ii;
      int L = g ^ ((g >> 3) & 7);
      int row = L >> 3, k8 = L & 7;
      GLDS16(Ab + (size_t)(bm + row) * 1024 + kt + k8 * 8, &As[buf][g * 8]);
    }
  };
  auto computeAB = [&](int bufA, int bufB) {
#pragma unroll
    for (int ks = 0; ks < 2; ++ks) {
      const int kb = ks * 64 + lg * 16;  // byte offset within a 128B row
      bf16x8 af[4], bf[2];
#pragma unroll
      for (int mf = 0; mf < 4; ++mf) {
        int row = wm * 64 + mf * 16 + l15;
        int byte = (row * 128 + kb) ^ ((row & 7) << 4);
        af[mf] = *reinterpret_cast<const bf16x8*>(
            reinterpret_cast<const char*>(As[bufA]) + byte);
      }
#pragma unroll
      for (int nf = 0; nf < 2; ++nf) {
        int row = wn * 32 + nf * 16 + l15;
        int byte = (row * 128 + kb) ^ ((row & 7) << 4);
        bf[nf] = *reinterpret_cast<const bf16x8*>(
            reinterpret_cast<const char*>(Bs[bufB]) + byte);
      }
#pragma unroll
      for (int mf = 0; mf < 4; ++mf)
#pragma unroll
        for (int nf = 0; nf < 2; ++nf)
          acc[mf][nf] = __builtin_amdgcn_mfma_f32_16x16x32_bf16(
              af[mf], bf[nf], acc[mf][nf], 0, 0, 0);
    }
  };

  stageA(0, 0);
  stageB(0, 0);
  stageA(1, 64);
  asm volatile("s_waitcnt vmcnt(2)" ::: "memory");
  __builtin_amdgcn_s_barrier();
  __builtin_amdgcn_sched_barrier(0);
  int aC = 0, bC = 0;
  for (int tt = 0; tt < 16; ++tt) {
    if (tt + 1 < 16) stageB(bC ^ 1, (tt + 1) * 64);
    if (tt + 2 < 16) stageA(aC >= 1 ? aC - 1 : aC + 2, (tt + 2) * 64);
    computeAB(aC, bC);
    if (tt < 15) {
      if (tt < 14) asm volatile("s_waitcnt vmcnt(2)" ::: "memory");
      else         asm volatile("s_waitcnt vmcnt(0)" ::: "memory");
      __builtin_amdgcn_s_barrier();
      __builtin_amdgcn_sched_barrier(0);
    }
    aC = (aC == 2) ? 0 : aC + 1;
    bC ^= 1;
  }

#pragma unroll
  for (int mf = 0; mf < 4; ++mf) {
#pragma unroll
    for (int nf = 0; nf < 2; ++nf) {
      int n = bn + wn * 32 + nf * 16 + l15;
      float bv = bias[n];
#pragma unroll
      for (int r = 0; r < 4; ++r) {
        int m = bm + wm * 64 + mf * 16 + lg * 4 + r;
        float v = (acc[mf][nf][r] + bv) * scale;
        uint16_t o = f2bf(v);
        int bb = m >> 10, s = m & 1023;
        if (isQ) {
          int h = n >> 6, d = n & 63;
          Qb[((((bb * 16 + h) << 10) | s) << 6) | d] = o;
        } else if (n < 1024) {
          int h = n >> 6, d = n & 63;
          Kb[((((bb * 16 + h) << 10) | s) << 6) | d] = o;
        } else {
          int n2 = n - 1024;
          int h = n2 >> 6, d = n2 & 63;
          Vb[((((bb * 16 + h) << 6) | d) << 10) | s] = o;
        }
      }
    }
  }
}

// -------- Fallback fused GEMM (256 threads, f32 A reg-staged; r12 path) ----
__global__ __launch_bounds__(256) void gemm_fb(
    const float* __restrict__ frF, const float* __restrict__ enF,
    const uint16_t* __restrict__ wq, const uint16_t* __restrict__ wkv,
    const float* __restrict__ bq, const float* __restrict__ bkv,
    const int* __restrict__ l_en_p, const int* __restrict__ l_fr_p,
    uint16_t* __restrict__ Qb, uint16_t* __restrict__ Kb,
    uint16_t* __restrict__ Vb) {
  __shared__ __attribute__((aligned(16))) uint16_t As[2][128 * 64];
  __shared__ __attribute__((aligned(16))) uint16_t Bs[2][128 * 64];
  const int t = threadIdx.x;
  const int lane = t & 63;
  const int w = t >> 6;
  const int wm = w >> 1, wn = w & 1;
  const int l15 = lane & 15, lg = lane >> 4;

  const int orig = blockIdx.x;
  const int xcd = orig & 7;
  const int slot = orig >> 3;
  const bool isQ = slot < 64;
  int b, bn;
  if (isQ) { b = slot >> 3; bn = (slot & 7) * 128; }
  else { int s2 = slot - 64; b = s2 >> 4; bn = (s2 & 15) * 128; }
  const int i = (xcd - b) & 7;
  const int bm = b * 1024 + i * 128;

  const int need = isQ ? read_len(l_fr_p, b) : read_len(l_en_p, b);
  if (i * 128 >= need) return;

  const uint16_t* Bw = isQ ? wq : wkv;
  const float* bias = isQ ? bq : bkv;
  const float scale = isQ ? 0.03125f : 1.0f;
  const float* Af = isQ ? frF : enF;

  f32x4 acc[4][4];
#pragma unroll
  for (int ii = 0; ii < 4; ++ii)
#pragma unroll
    for (int j = 0; j < 4; ++j) acc[ii][j] = (f32x4){0.f, 0.f, 0.f, 0.f};

  float4 ar0[4], ar1[4];

  auto stageB = [&](int buf, int kt) {
#pragma unroll
    for (int ii = 0; ii < 4; ++ii) {
      int g = t + 256 * ii;
      int L = g ^ ((g >> 3) & 7);
      int row = L >> 3, k8 = L & 7;
      GLDS16(Bw + (size_t)(bn + row) * 1024 + kt + k8 * 8, &Bs[buf][g * 8]);
    }
  };
  auto loadA_f32 = [&](int kt) {
#pragma unroll
    for (int ii = 0; ii < 4; ++ii) {
      int L = t + 256 * ii;
      int row = L >> 3, k8 = L & 7;
      const float* src = Af + (size_t)(bm + row) * 1024 + kt + k8 * 8;
      ar0[ii] = *reinterpret_cast<const float4*>(src);
      ar1[ii] = *reinterpret_cast<const float4*>(src + 4);
    }
  };
  auto writeA = [&](int buf) {
#pragma unroll
    for (int ii = 0; ii < 4; ++ii) {
      int L = t + 256 * ii;
      int row = L >> 3, k8 = L & 7;
      ushortx8 o;
      o[0] = f2bf(ar0[ii].x); o[1] = f2bf(ar0[ii].y);
      o[2] = f2bf(ar0[ii].z); o[3] = f2bf(ar0[ii].w);
      o[4] = f2bf(ar1[ii].x); o[5] = f2bf(ar1[ii].y);
      o[6] = f2bf(ar1[ii].z); o[7] = f2bf(ar1[ii].w);
      int byte = (row * 128 + k8 * 16) ^ ((row & 7) << 4);
      *reinterpret_cast<ushortx8*>(reinterpret_cast<char*>(As[buf]) + byte) = o;
    }
  };
  auto compute = [&](int buf) {
#pragma unroll
    for (int ks = 0; ks < 2; ++ks) {
      const int kb = ks * 64 + lg * 16;
      bf16x8 af[4], bf[4];
#pragma unroll
      for (int mf = 0; mf < 4; ++mf) {
        int row = wm * 64 + mf * 16 + l15;
        int byte = (row * 128 + kb) ^ ((row & 7) << 4);
        af[mf] = *reinterpret_cast<const bf16x8*>(
            reinterpret_cast<const char*>(As[buf]) + byte);
      }
#pragma unroll
      for (int nf = 0; nf < 4; ++nf) {
        int row = wn * 64 + nf * 16 + l15;
        int byte = (row * 128 + kb) ^ ((row & 7) << 4);
        bf[nf] = *reinterpret_cast<const bf16x8*>(
            reinterpret_cast<const char*>(Bs[buf]) + byte);
      }
#pragma unroll
      for (int mf = 0; mf < 4; ++mf)
#pragma unroll
        for (int nf = 0; nf < 4; ++nf)
          acc[mf][nf] = __builtin_amdgcn_mfma_f32_16x16x32_bf16(
              af[mf], bf[nf], acc[mf][nf], 0, 0, 0);
    }
  };
  loadA_f32(0);
  stageB(0, 0);
  writeA(0);
  __syncthreads();
#pragma unroll 2
  for (int tt = 0; tt < 16; ++tt) {
    const int cur = tt & 1;
    const int ktn = (tt + 1) * 64;
    if (tt < 15) { stageB(cur ^ 1, ktn); loadA_f32(ktn); }
    compute(cur);
    if (tt < 15) writeA(cur ^ 1);
    __syncthreads();
  }

#pragma unroll
  for (int mf = 0; mf < 4; ++mf) {
#pragma unroll
    for (int nf = 0; nf < 4; ++nf) {
      int n = bn + wn * 64 + nf * 16 + l15;
      float bv = bias[n];
#pragma unroll
      for (int r = 0; r < 4; ++r) {
        int m = bm + wm * 64 + mf * 16 + lg * 4 + r;
        float v = (acc[mf][nf][r] + bv) * scale;
        uint16_t o = f2bf(v);
        int bb = m >> 10, s = m & 1023;
        if (isQ) {
          int h = n >> 6, d = n & 63;
          Qb[((((bb * 16 + h) << 10) | s) << 6) | d] = o;
        } else if (n < 1024) {
          int h = n >> 6, d = n & 63;
          Kb[((((bb * 16 + h) << 10) | s) << 6) | d] = o;
        } else {
          int n2 = n - 1024;
          int h = n2 >> 6, d = n2 & 63;
          Vb[((((bb * 16 + h) << 6) | d) << 10) | s] = o;
        }
      }
    }
  }
}

// ---------------- Flash attention (r17 + counted-vmcnt 3-deep K/V ring) ----
// 1024 blocks x 512 threads (8 waves), QBLK=128, defer-max (THR=8), T5
// setprio, balanced XCD mapping (XCD = h&7). K/V 3-deep ring staged 2 tiles
// ahead; `s_waitcnt vmcnt(2)` (never 0 mid-loop); raw s_barrier +
// sched_barrier(0) (rule #18). Safety: each wave's own GLDS writes for tile
// t+1 are vmcnt-drained before its barrier; ds_reads consumed by MFMAs
// pre-barrier; Ps is wave-private.
__global__ __launch_bounds__(512) void attn_kernel(
    const uint16_t* __restrict__ Qb,  // [B,H,S,DH] bf16, pre-scaled
    const uint16_t* __restrict__ Kb,  // [B,H,S,DH] bf16
    const uint16_t* __restrict__ Vt,  // [B,H,DH,S] bf16
    const int* __restrict__ l_en_p, const int* __restrict__ l_fr_p,
    float* __restrict__ out) {        // [B,S,D] f32
  __shared__ __attribute__((aligned(16))) uint16_t Ks[3][64 * 64];
  __shared__ __attribute__((aligned(16))) uint16_t Vs[3][64 * 64];
  __shared__ __attribute__((aligned(16))) bf16_t Ps[8][16][72];
  const int t = threadIdx.x;
  const int lane = t & 63, w = t >> 6;          // w in 0..7
  const int l15 = lane & 15, lg = lane >> 4;
  const int orig = blockIdx.x;
  const int xcd = orig & 7;
  const int slot = orig >> 3;                  // 0..127
  const int b = slot >> 4;
  const int rest = slot & 15;
  const int h = xcd + 8 * (rest >> 3);
  const int q0 = (rest & 7) << 7;              // 128-row tile
  const int bh = b * 16 + h;
  const int len_en = read_len(l_en_p, b);
  const int len_fr = read_len(l_fr_p, b);

  if (q0 >= len_fr) {
    for (int i = t; i < 128 * 64; i += 512) {
      int rr = i >> 6, cc = i & 63;
      out[(size_t)(b * 1024 + q0 + rr) * 1024 + h * 64 + cc] = 0.f;
    }
    return;
  }

  const uint16_t* qbase =
      Qb + ((size_t)bh * 1024 + q0 + w * 16 + l15) * 64 + lg * 8;
  const bf16x8 aq0 = *reinterpret_cast<const bf16x8*>(qbase);
  const bf16x8 aq1 = *reinterpret_cast<const bf16x8*>(qbase + 32);

  float mrow[4], lrow[4];
  f32x4 oacc[4];
#pragma unroll
  for (int r = 0; r < 4; ++r) { mrow[r] = -1e30f; lrow[r] = 0.f; }
#pragma unroll
  for (int df = 0; df < 4; ++df) oacc[df] = (f32x4){0.f, 0.f, 0.f, 0.f};

  auto stage = [&](int buf, int j0) {
    int g = t;
    int L = g ^ ((g >> 3) & 7);
    int row = L >> 3, k8 = L & 7;
    GLDS16(Kb + ((size_t)bh * 1024 + j0 + row) * 64 + k8 * 8, &Ks[buf][g * 8]);
    GLDS16(Vt + ((size_t)bh * 64 + row) * 1024 + j0 + k8 * 8, &Vs[buf][g * 8]);
  };

  const int ntiles = (len_en + 63) >> 6;
  stage(0, 0);
  if (ntiles > 1) {
    stage(1, 64);
    asm volatile("s_waitcnt vmcnt(2)" ::: "memory");
  } else {
    asm volatile("s_waitcnt vmcnt(0)" ::: "memory");
  }
  __builtin_amdgcn_s_barrier();
  __builtin_amdgcn_sched_barrier(0);

  int cur = 0;
  for (int tt = 0; tt < ntiles; ++tt) {
    const int j0 = tt * 64;
    if (tt + 2 < ntiles) stage(cur >= 1 ? cur - 1 : 2, (tt + 2) * 64);

    f32x4 sc[4];
#pragma unroll
    for (int nf = 0; nf < 4; ++nf) sc[nf] = (f32x4){0.f, 0.f, 0.f, 0.f};
    __builtin_amdgcn_s_setprio(1);
#pragma unroll
    for (int ks = 0; ks < 2; ++ks) {
      const bf16x8 aq = ks ? aq1 : aq0;
      const int kb = ks * 64 + lg * 16;
#pragma unroll
      for (int nf = 0; nf < 4; ++nf) {
        int row = nf * 16 + l15;
        int byte = (row * 128 + kb) ^ ((row & 7) << 4);
        bf16x8 bk = *reinterpret_cast<const bf16x8*>(
            reinterpret_cast<const char*>(Ks[cur]) + byte);
        sc[nf] = __builtin_amdgcn_mfma_f32_16x16x32_bf16(aq, bk, sc[nf], 0, 0, 0);
      }
    }
    __builtin_amdgcn_s_setprio(0);
#pragma unroll
    for (int nf = 0; nf < 4; ++nf) {
      int col = j0 + nf * 16 + l15;
      if (col >= len_en) sc[nf] = (f32x4){-1e30f, -1e30f, -1e30f, -1e30f};
    }
    float tm[4];
#pragma unroll
    for (int r = 0; r < 4; ++r)
      tm[r] = fmaxf(fmaxf(sc[0][r], sc[1][r]), fmaxf(sc[2][r], sc[3][r]));
#pragma unroll
    for (int off = 1; off < 16; off <<= 1)
#pragma unroll
      for (int r = 0; r < 4; ++r) tm[r] = fmaxf(tm[r], __shfl_xor(tm[r], off));

    bool small = (tm[0] <= mrow[0] + 8.f) && (tm[1] <= mrow[1] + 8.f) &&
                 (tm[2] <= mrow[2] + 8.f) && (tm[3] <= mrow[3] + 8.f);
    if (!__all(small)) {
      float fac[4];
#pragma unroll
      for (int r = 0; r < 4; ++r) {
        float mn = fmaxf(mrow[r], tm[r]);
        fac[r] = __expf(mrow[r] - mn);
        mrow[r] = mn;
      }
#pragma unroll
      for (int r = 0; r < 4; ++r) lrow[r] *= fac[r];
#pragma unroll
      for (int df = 0; df < 4; ++df)
#pragma unroll
        for (int r = 0; r < 4; ++r) oacc[df][r] *= fac[r];
    }
    float ps[4] = {0.f, 0.f, 0.f, 0.f};
#pragma unroll
    for (int nf = 0; nf < 4; ++nf)
#pragma unroll
      for (int r = 0; r < 4; ++r) {
        float p = __expf(sc[nf][r] - mrow[r]);
        ps[r] += p;
        Ps[w][lg * 4 + r][nf * 16 + l15] = (bf16_t)p;
      }
#pragma unroll
    for (int off = 1; off < 16; off <<= 1)
#pragma unroll
      for (int r = 0; r < 4; ++r) ps[r] += __shfl_xor(ps[r], off);
#pragma unroll
    for (int r = 0; r < 4; ++r) lrow[r] += ps[r];

    __builtin_amdgcn_s_setprio(1);
#pragma unroll
    for (int ks = 0; ks < 2; ++ks) {
      const bf16x8 pa = *reinterpret_cast<const bf16x8*>(
          &Ps[w][l15][0] + ks * 32 + lg * 8);
#pragma unroll
      for (int df = 0; df < 4; ++df) {
        int row = df * 16 + l15;
        int byte = (row * 128 + ks * 64 + lg * 16) ^ ((row & 7) << 4);
        bf16x8 bv = *reinterpret_cast<const bf16x8*>(
            reinterpret_cast<const char*>(Vs[cur]) + byte);
        oacc[df] = __builtin_amdgcn_mfma_f32_16x16x32_bf16(pa, bv, oacc[df], 0, 0, 0);
      }
    }
    __builtin_amdgcn_s_setprio(0);

    if (tt + 1 < ntiles) {
      if (tt + 2 < ntiles) asm volatile("s_waitcnt vmcnt(2)" ::: "memory");
      else                 asm volatile("s_waitcnt vmcnt(0)" ::: "memory");
      __builtin_amdgcn_s_barrier();
      __builtin_amdgcn_sched_barrier(0);
    }
    cur = (cur == 2) ? 0 : cur + 1;
  }

#pragma unroll
  for (int df = 0; df < 4; ++df)
#pragma unroll
    for (int r = 0; r < 4; ++r) {
      int q = q0 + w * 16 + lg * 4 + r;
      float inv = (q < len_fr && lrow[r] > 0.f) ? 1.0f / lrow[r] : 0.f;
      out[(size_t)(b * 1024 + q) * 1024 + h * 64 + df * 16 + l15] =
          oacc[df][r] * inv;
    }
}

// ---------------- launch ----------------
extern "C" void kernel_launch(void* const* d_in, const int* in_sizes, int n_in,
                              void* d_out, int out_size, void* d_ws,
                              size_t ws_size, hipStream_t stream) {
  const float* en = (const float*)d_in[0];
  const float* fr = (const float*)d_in[1];
  const int* l_en = (const int*)d_in[2];
  const int* l_fr = (const int*)d_in[3];
  const float* wq = (const float*)d_in[4];
  const float* bq = (const float*)d_in[5];
  const float* wkv = (const float*)d_in[6];
  const float* bkv = (const float*)d_in[7];
  float* out = (float*)d_out;  // output dtype is FLOAT32

  // Workspace layout (bytes):
  // wq_bf 0..2M | wkv_bf 2M..6M | Qbuf 6M..23M | Kbuf 23M..40M | Vtbuf 40M..56.6M
  // [fast path] fr_bf 56.6M..73.4M | en_bf 73.4M..90.2M
  char* ws = (char*)d_ws;
  uint16_t* wq_bf = (uint16_t*)(ws);
  uint16_t* wkv_bf = (uint16_t*)(ws + 2097152);
  uint16_t* Qbuf = (uint16_t*)(ws + 6291456);
  uint16_t* Kbuf = (uint16_t*)(ws + 23068672);
  uint16_t* Vtbuf = (uint16_t*)(ws + 39845888);
  uint16_t* fr_bf = (uint16_t*)(ws + 56623104);
  uint16_t* en_bf = (uint16_t*)(ws + 73400320);
  const bool pre = ws_size >= 90177536ull;

  if (pre) {
    // (fr + en + wq + wkv) elems / 8 per thread / 256 per block = 9728 blocks
    cvt4_kernel<<<9728, 256, 0, stream>>>(fr, fr_bf, 8388608,
                                          en, en_bf, 8388608,
                                          wq, wq_bf, 1048576,
                                          wkv, wkv_bf, 2097152,
                                          l_fr, l_en);
    gemm_fast<<<1536, 512, 0, stream>>>(fr_bf, en_bf, wq_bf, wkv_bf, bq, bkv,
                                        l_en, l_fr, Qbuf, Kbuf, Vtbuf);
  } else {
    // weights only: (1M + 2M)/8/256 = 1536 blocks
    cvt4_kernel<<<1536, 256, 0, stream>>>(wq, wq_bf, 1048576,
                                          wkv, wkv_bf, 2097152,
                                          nullptr, nullptr, 0,
                                          nullptr, nullptr, 0,
                                          nullptr, nullptr);
    gemm_fb<<<1536, 256, 0, stream>>>(fr, en, wq_bf, wkv_bf, bq, bkv,
                                      l_en, l_fr, Qbuf, Kbuf, Vtbuf);
  }

  attn_kernel<<<1024, 512, 0, stream>>>(Qbuf, Kbuf, Vtbuf, l_en, l_fr, out);
}